// Round 1
// baseline (3845.853 us; speedup 1.0000x reference)
//
#include <hip/hip_runtime.h>
#include <cstddef>
#include <cstdint>

// Problem constants
#define B_DIM   4
#define L_SEQ   2048
#define C_DIM   2048
#define OUT_DIM 768
#define NHEADS  32
#define HDIM    64
#define MBS_    16
#define NMINI   128
#define EPS_    1e-6f

// ======================================================================
// SGEMM fp32: C[m,n] = sum_k A[m,k] * B[k,n]
// Tile 128x128, BK=16, 256 threads, 8x8 micro-tile.
// mode 0: scatter into (B,NH,L,HD) head-layout tensor (N must be 2048)
// mode 1: plain row-major C (ldc = N)
// ======================================================================
__global__ __launch_bounds__(256)
void sgemm_kernel(const float* __restrict__ A, const float* __restrict__ Bm,
                  float* __restrict__ C, int N, int K, int mode)
{
    __shared__ float As[16][132];   // As[k][m]
    __shared__ float Bs[16][132];   // Bs[k][n]
    const int tid = threadIdx.x;
    const int tx = tid & 15, ty = tid >> 4;
    const int bm = blockIdx.y * 128, bn = blockIdx.x * 128;

    float acc[8][8];
#pragma unroll
    for (int r = 0; r < 8; r++)
#pragma unroll
        for (int c = 0; c < 8; c++) acc[r][c] = 0.0f;

    const int ar = tid >> 2, ac4 = (tid & 3) * 4;
    const int br = tid >> 4, bc8 = (tid & 15) * 8;
    const float* Aptr0 = A + (size_t)(bm + ar) * K + ac4;
    const float* Aptr1 = A + (size_t)(bm + ar + 64) * K + ac4;
    const float* Bptr  = Bm + (size_t)br * N + bn + bc8;

    for (int k0 = 0; k0 < K; k0 += 16) {
        const float4 a0 = *(const float4*)(Aptr0 + k0);
        const float4 a1 = *(const float4*)(Aptr1 + k0);
        const float4 b0 = *(const float4*)(Bptr + (size_t)k0 * N);
        const float4 b1 = *(const float4*)(Bptr + (size_t)k0 * N + 4);
        As[ac4 + 0][ar] = a0.x; As[ac4 + 1][ar] = a0.y;
        As[ac4 + 2][ar] = a0.z; As[ac4 + 3][ar] = a0.w;
        As[ac4 + 0][ar + 64] = a1.x; As[ac4 + 1][ar + 64] = a1.y;
        As[ac4 + 2][ar + 64] = a1.z; As[ac4 + 3][ar + 64] = a1.w;
        *(float4*)&Bs[br][bc8]     = b0;
        *(float4*)&Bs[br][bc8 + 4] = b1;
        __syncthreads();
#pragma unroll
        for (int k = 0; k < 16; k++) {
            const float4 aa0 = *(const float4*)&As[k][ty * 8];
            const float4 aa1 = *(const float4*)&As[k][ty * 8 + 4];
            const float4 bb0 = *(const float4*)&Bs[k][tx * 8];
            const float4 bb1 = *(const float4*)&Bs[k][tx * 8 + 4];
            const float a8[8] = {aa0.x, aa0.y, aa0.z, aa0.w, aa1.x, aa1.y, aa1.z, aa1.w};
            const float b8[8] = {bb0.x, bb0.y, bb0.z, bb0.w, bb1.x, bb1.y, bb1.z, bb1.w};
#pragma unroll
            for (int r = 0; r < 8; r++)
#pragma unroll
                for (int c = 0; c < 8; c++) acc[r][c] += a8[r] * b8[c];
        }
        __syncthreads();
    }

    if (mode == 1) {
#pragma unroll
        for (int r = 0; r < 8; r++) {
            const int m = bm + ty * 8 + r;
            float* dst = C + (size_t)m * N + bn + tx * 8;
            float4 o0, o1;
            o0.x = acc[r][0]; o0.y = acc[r][1]; o0.z = acc[r][2]; o0.w = acc[r][3];
            o1.x = acc[r][4]; o1.y = acc[r][5]; o1.z = acc[r][6]; o1.w = acc[r][7];
            *(float4*)dst = o0; *(float4*)(dst + 4) = o1;
        }
    } else {
        const int ncol = bn + tx * 8;           // 0..2047 within this matrix
        const int h = ncol >> 6, d0 = ncol & 63;
#pragma unroll
        for (int r = 0; r < 8; r++) {
            const int m = bm + ty * 8 + r;
            const int b = m >> 11, l = m & 2047;
            float* dst = C + ((size_t)(b * NHEADS + h) * L_SEQ + l) * HDIM + d0;
            float4 o0, o1;
            o0.x = acc[r][0]; o0.y = acc[r][1]; o0.z = acc[r][2]; o0.w = acc[r][3];
            o1.x = acc[r][4]; o1.y = acc[r][5]; o1.z = acc[r][6]; o1.w = acc[r][7];
            *(float4*)dst = o0; *(float4*)(dst + 4) = o1;
        }
    }
}

// ======================================================================
// ttt_lr: lrs[(b*NH+h)*L + l] = sigmoid(hidden[b,l,:] . wlr[h,:] + bias[h])
// one block per (b,l) row, 256 threads: 32 heads x 8-way K-split
// ======================================================================
__global__ __launch_bounds__(256)
void lr_kernel(const float* __restrict__ hidden, const float* __restrict__ wlr,
               const float* __restrict__ lr_bias, float* __restrict__ lrs)
{
    __shared__ float sRow[2048];
    __shared__ float sPart[32][9];
    const int m = blockIdx.x;          // b*L + l
    const int t = threadIdx.x;
    const float* row = hidden + (size_t)m * C_DIM;
#pragma unroll
    for (int j = 0; j < 8; j++) sRow[t + j * 256] = row[t + j * 256];
    __syncthreads();
    const int h = t >> 3, p = t & 7;
    const float* w = wlr + (size_t)h * C_DIM;
    float s = 0.0f;
#pragma unroll 8
    for (int k = 0; k < 64; k++) {
        const int c = k * 32 + p * 4;   // staggered to avoid LDS bank conflicts
        const float4 a = *(const float4*)(sRow + c);
        const float4 b = *(const float4*)(w + c);
        s += a.x * b.x + a.y * b.y + a.z * b.z + a.w * b.w;
    }
    sPart[h][p] = s;
    __syncthreads();
    if (t < 32) {
        float v = 0.0f;
#pragma unroll
        for (int p2 = 0; p2 < 8; p2++) v += sPart[t][p2];
        v += lr_bias[t];
        const float sig = 1.0f / (1.0f + expf(-v));
        lrs[((size_t)(m >> 11) * NHEADS + t) * L_SEQ + (m & 2047)] = sig;
    }
}

// ======================================================================
// RoPE (net effect of permute/rotate_half/unpermute = interleaved pairs)
// X layout (B,NH,L,HD); angle_i = (pos % 16) * 10000^(-i/32), i = pair idx
// ======================================================================
__global__ __launch_bounds__(256)
void rope_kernel(float* __restrict__ X, const int* __restrict__ pos_ids)
{
    const int idx = blockIdx.x * 256 + threadIdx.x;   // B*NH*L*32 threads
    const int r = idx >> 5, ii = idx & 31;
    const int l = r & 2047;
    const int b = r >> 16;                            // NH*L = 65536
    const int p = pos_ids[(b << 11) + l] & 15;        // % MBS
    const float angle = (float)p * expf(-(float)ii * 0.28782313662425574f); // ln(1e4)/32
    float s, c;
    sincosf(angle, &s, &c);
    float2* ptr = (float2*)(X + (size_t)r * HDIM + ii * 2);
    const float2 x = *ptr;
    float2 o;
    o.x = x.x * c - x.y * s;
    o.y = x.y * c + x.x * s;
    *ptr = o;
}

// ======================================================================
// TTT scan: one block per (b,h), 256 threads, sequential over NM=128 steps.
// State W1 (64x64) + b1 (64) in LDS, fp32 throughout.
// Writes out in-place over XV.
// ======================================================================
__global__ __launch_bounds__(256)
void scan_kernel(const float* __restrict__ XQ, const float* __restrict__ XK,
                 float* __restrict__ XVo, const float* __restrict__ LRS,
                 const float* __restrict__ W1i, const float* __restrict__ b1i,
                 const float* __restrict__ lt, const float* __restrict__ lnw,
                 const float* __restrict__ lnb)
{
    __shared__ float sW1[64][68];
    __shared__ float sXq[16][68], sXk[16][68], sXv[16][68], sGrad[16][68];
    __shared__ float sCoeff[16][16];
    __shared__ float sB1[64], sGamma[64], sBeta[64];
    __shared__ float sEta[16], sTok[16];

    const int bh = blockIdx.x;          // b*NH + h
    const int h = bh & 31;
    const int t = threadIdx.x;
#pragma unroll
    for (int r = 0; r < 16; r++) {
        const int idx = t + r * 256;
        sW1[idx >> 6][idx & 63] = W1i[h * 4096 + idx];
    }
    if (t < 64) {
        sB1[t] = b1i[h * 64 + t];
        sGamma[t] = lnw[h * 64 + t];
        sBeta[t] = lnb[h * 64 + t];
    }
    if (t < 16) sTok[t] = fmaxf(1.0f / (float)(t + 1) + lt[t], 0.0f);

    const size_t base = (size_t)bh * L_SEQ * HDIM;
    const float* xq_g = XQ + base;
    const float* xk_g = XK + base;
    float* xv_g = XVo + base;
    const float* lr_g = LRS + (size_t)bh * L_SEQ;
    const int i = t >> 4, lane = t & 15, d0 = lane * 4;
    __syncthreads();

    for (int n = 0; n < NMINI; n++) {
        // ---- phase 1: load minibatch ----
        {
            const int off = n * (MBS_ * HDIM) + t * 4;
            const float4 q = *(const float4*)(xq_g + off);
            const float4 kk = *(const float4*)(xk_g + off);
            const float4 vv = *(const float4*)(xv_g + off);
            *(float4*)&sXq[i][d0] = q;
            *(float4*)&sXk[i][d0] = kk;
            *(float4*)&sXv[i][d0] = vv;
            if (t < 16) sEta[t] = lr_g[n * MBS_ + t] * (1.0f / 64.0f);
        }
        __syncthreads();

        // ---- phase 2: Z1 = xk@W1 + b1 (and xq@W1 saved); LN-L2 grad; coeff ----
        float z[4] = {0, 0, 0, 0}, xqw[4] = {0, 0, 0, 0};
#pragma unroll
        for (int k4 = 0; k4 < 16; k4++) {
            const float4 xk4 = *(const float4*)&sXk[i][k4 * 4];
            const float4 xq4 = *(const float4*)&sXq[i][k4 * 4];
            const float kx[4] = {xk4.x, xk4.y, xk4.z, xk4.w};
            const float qx[4] = {xq4.x, xq4.y, xq4.z, xq4.w};
#pragma unroll
            for (int kk = 0; kk < 4; kk++) {
                const float4 w = *(const float4*)&sW1[k4 * 4 + kk][d0];
                z[0] += kx[kk] * w.x; z[1] += kx[kk] * w.y;
                z[2] += kx[kk] * w.z; z[3] += kx[kk] * w.w;
                xqw[0] += qx[kk] * w.x; xqw[1] += qx[kk] * w.y;
                xqw[2] += qx[kk] * w.z; xqw[3] += qx[kk] * w.w;
            }
        }
#pragma unroll
        for (int c = 0; c < 4; c++) z[c] += sB1[d0 + c];

        float s1 = z[0] + z[1] + z[2] + z[3];
        float s2 = z[0] * z[0] + z[1] * z[1] + z[2] * z[2] + z[3] * z[3];
#pragma unroll
        for (int o = 1; o < 16; o <<= 1) { s1 += __shfl_xor(s1, o); s2 += __shfl_xor(s2, o); }
        const float mu = s1 * (1.0f / 64.0f);
        const float var = s2 * (1.0f / 64.0f) - mu * mu;
        const float rstd = rsqrtf(var + EPS_);
        float gg[4], xh[4];
        float sg = 0.0f, sgx = 0.0f;
#pragma unroll
        for (int c = 0; c < 4; c++) {
            xh[c] = (z[c] - mu) * rstd;
            const float ga = sGamma[d0 + c];
            const float y = ga * xh[c] + sBeta[d0 + c];
            const float tgt = sXv[i][d0 + c] - sXk[i][d0 + c];
            gg[c] = (y - tgt) * ga;
            sg += gg[c];
            sgx += gg[c] * xh[c];
        }
#pragma unroll
        for (int o = 1; o < 16; o <<= 1) { sg += __shfl_xor(sg, o); sgx += __shfl_xor(sgx, o); }
        {
            const float sc = rstd * (1.0f / 64.0f);
            float4 gr;
            gr.x = (64.0f * gg[0] - sg - xh[0] * sgx) * sc;
            gr.y = (64.0f * gg[1] - sg - xh[1] * sgx) * sc;
            gr.z = (64.0f * gg[2] - sg - xh[2] * sgx) * sc;
            gr.w = (64.0f * gg[3] - sg - xh[3] * sgx) * sc;
            *(float4*)&sGrad[i][d0] = gr;
        }
        // coeff[i][j] = (j<=i) ? tok[i]*eta[j]*(xq_i . xk_j + 1) : 0
        {
            float a = 0.0f;
#pragma unroll
            for (int k4 = 0; k4 < 16; k4++) {
                const float4 qa = *(const float4*)&sXq[i][k4 * 4];
                const float4 kb = *(const float4*)&sXk[lane][k4 * 4];
                a += qa.x * kb.x + qa.y * kb.y + qa.z * kb.z + qa.w * kb.w;
            }
            sCoeff[i][lane] = (lane <= i) ? sTok[i] * sEta[lane] * (a + 1.0f) : 0.0f;
        }
        __syncthreads();

        // ---- phase 3: Z1_bar, LN-fwd, out = xq + ln(Z1_bar) ----
        float zb[4];
#pragma unroll
        for (int c = 0; c < 4; c++) zb[c] = xqw[c] + sB1[d0 + c];
#pragma unroll
        for (int j = 0; j < 16; j++) {
            const float cf = sCoeff[i][j];
            const float4 g4 = *(const float4*)&sGrad[j][d0];
            zb[0] -= cf * g4.x; zb[1] -= cf * g4.y;
            zb[2] -= cf * g4.z; zb[3] -= cf * g4.w;
        }
        float u1 = zb[0] + zb[1] + zb[2] + zb[3];
        float u2 = zb[0] * zb[0] + zb[1] * zb[1] + zb[2] * zb[2] + zb[3] * zb[3];
#pragma unroll
        for (int o = 1; o < 16; o <<= 1) { u1 += __shfl_xor(u1, o); u2 += __shfl_xor(u2, o); }
        const float mu2 = u1 * (1.0f / 64.0f);
        const float var2 = u2 * (1.0f / 64.0f) - mu2 * mu2;
        const float rstd2 = rsqrtf(var2 + EPS_);
        {
            float4 outv;
            outv.x = sXq[i][d0 + 0] + sGamma[d0 + 0] * ((zb[0] - mu2) * rstd2) + sBeta[d0 + 0];
            outv.y = sXq[i][d0 + 1] + sGamma[d0 + 1] * ((zb[1] - mu2) * rstd2) + sBeta[d0 + 1];
            outv.z = sXq[i][d0 + 2] + sGamma[d0 + 2] * ((zb[2] - mu2) * rstd2) + sBeta[d0 + 2];
            outv.w = sXq[i][d0 + 3] + sGamma[d0 + 3] * ((zb[3] - mu2) * rstd2) + sBeta[d0 + 3];
            *(float4*)(xv_g + n * (MBS_ * HDIM) + t * 4) = outv;
        }
        __syncthreads();

        // ---- phase 4: state update (uses OLD-state grad, eta) ----
        {
            const float T15 = sTok[15];
            const int d = t >> 2, e0 = (t & 3) * 16;
            float acc[16];
#pragma unroll
            for (int e = 0; e < 16; e++) acc[e] = 0.0f;
#pragma unroll
            for (int j = 0; j < 16; j++) {
                const float lj = sEta[j] * sXk[j][d];
                const float* gr = &sGrad[j][e0];
#pragma unroll
                for (int e = 0; e < 16; e++) acc[e] += lj * gr[e];
            }
            float* wr = &sW1[d][e0];
#pragma unroll
            for (int e = 0; e < 16; e++) wr[e] -= T15 * acc[e];
            if (t < 64) {
                float s = 0.0f;
#pragma unroll
                for (int j = 0; j < 16; j++) s += sEta[j] * sGrad[j][t];
                sB1[t] -= T15 * s;
            }
        }
        __syncthreads();
    }
}

// ======================================================================
// post-norm: gather (B,NH,L,HD) -> row of C=2048, LN, write (B,L,C)
// ======================================================================
__global__ __launch_bounds__(256)
void postln_kernel(const float* __restrict__ Ob, const float* __restrict__ pnw,
                   const float* __restrict__ pnb, float* __restrict__ XN)
{
    const int m = blockIdx.x;            // b*L + l
    const int b = m >> 11, l = m & 2047;
    const int t = threadIdx.x;
    float v[8];
    float s1 = 0.0f, s2 = 0.0f;
    const float* bas = Ob + (size_t)b * NHEADS * L_SEQ * HDIM + (size_t)l * HDIM;
#pragma unroll
    for (int j = 0; j < 8; j++) {
        const int c = t + j * 256;
        const int hh = c >> 6, d = c & 63;
        const float x = bas[(size_t)hh * (L_SEQ * HDIM) + d];
        v[j] = x; s1 += x; s2 += x * x;
    }
#pragma unroll
    for (int o = 1; o < 64; o <<= 1) { s1 += __shfl_xor(s1, o); s2 += __shfl_xor(s2, o); }
    __shared__ float r1[4], r2[4];
    const int w = t >> 6;
    if ((t & 63) == 0) { r1[w] = s1; r2[w] = s2; }
    __syncthreads();
    s1 = r1[0] + r1[1] + r1[2] + r1[3];
    s2 = r2[0] + r2[1] + r2[2] + r2[3];
    const float mu = s1 * (1.0f / 2048.0f);
    const float var = s2 * (1.0f / 2048.0f) - mu * mu;
    const float rstd = rsqrtf(var + EPS_);
    float* o = XN + (size_t)m * C_DIM;
#pragma unroll
    for (int j = 0; j < 8; j++) {
        const int c = t + j * 256;
        o[c] = (v[j] - mu) * rstd * pnw[c] + pnb[c];
    }
}

// ======================================================================
extern "C" void kernel_launch(void* const* d_in, const int* in_sizes, int n_in,
                              void* d_out, int out_size, void* d_ws, size_t ws_size,
                              hipStream_t stream)
{
    (void)in_sizes; (void)n_in; (void)out_size; (void)ws_size;
    const float* hidden  = (const float*)d_in[0];
    const int*   pos_ids = (const int*)d_in[1];
    const float* Wq      = (const float*)d_in[2];
    const float* Wk      = (const float*)d_in[3];
    const float* Wv      = (const float*)d_in[4];
    const float* Wo      = (const float*)d_in[5];
    const float* W1      = (const float*)d_in[6];
    const float* b1      = (const float*)d_in[7];
    const float* wlr     = (const float*)d_in[8];
    const float* lr_bias = (const float*)d_in[9];
    const float* lt      = (const float*)d_in[10];
    const float* lnw     = (const float*)d_in[11];
    const float* lnb     = (const float*)d_in[12];
    const float* pnw     = (const float*)d_in[13];
    const float* pnb     = (const float*)d_in[14];

    const size_t TEN = (size_t)B_DIM * NHEADS * L_SEQ * HDIM;  // 16777216
    float* XQ  = (float*)d_ws;
    float* XK  = XQ + TEN;
    float* XVo = XK + TEN;
    float* LRS = XVo + TEN;      // B*NH*L = 262144
    float* XN  = XQ;             // reuse after scan consumes XQ

    const dim3 blk(256);
    // QKV projections with transpose-scatter epilogue
    sgemm_kernel<<<dim3(16, 64), blk, 0, stream>>>(hidden, Wq, XQ,  C_DIM, C_DIM, 0);
    sgemm_kernel<<<dim3(16, 64), blk, 0, stream>>>(hidden, Wk, XK,  C_DIM, C_DIM, 0);
    sgemm_kernel<<<dim3(16, 64), blk, 0, stream>>>(hidden, Wv, XVo, C_DIM, C_DIM, 0);
    // ttt_lr sigmoid
    lr_kernel<<<dim3(B_DIM * L_SEQ), blk, 0, stream>>>(hidden, wlr, lr_bias, LRS);
    // RoPE on XQ, XK
    rope_kernel<<<dim3(32768), blk, 0, stream>>>(XQ, pos_ids);
    rope_kernel<<<dim3(32768), blk, 0, stream>>>(XK, pos_ids);
    // sequential TTT scan (out written over XV)
    scan_kernel<<<dim3(B_DIM * NHEADS), blk, 0, stream>>>(XQ, XK, XVo, LRS,
                                                          W1, b1, lt, lnw, lnb);
    // post layernorm (gather head layout -> (B,L,C))
    postln_kernel<<<dim3(B_DIM * L_SEQ), blk, 0, stream>>>(XVo, pnw, pnb, XN);
    // output projection
    sgemm_kernel<<<dim3(6, 64), blk, 0, stream>>>(XN, Wo, (float*)d_out, OUT_DIM, C_DIM, 1);
}

// Round 2
// 3729.279 us; speedup vs baseline: 1.0313x; 1.0313x over previous
//
#include <hip/hip_runtime.h>
#include <cstddef>
#include <cstdint>

// Problem constants
#define B_DIM   4
#define L_SEQ   2048
#define C_DIM   2048
#define OUT_DIM 768
#define NHEADS  32
#define HDIM    64
#define MBS_    16
#define NMINI   128
#define EPS_    1e-6f

typedef _Float16 half8 __attribute__((ext_vector_type(8)));
typedef _Float16 half4v __attribute__((ext_vector_type(4)));
typedef float floatx4 __attribute__((ext_vector_type(4)));

__device__ __forceinline__ void glds16(const void* g, void* l) {
    __builtin_amdgcn_global_load_lds(
        (const __attribute__((address_space(1))) uint32_t*)g,
        (__attribute__((address_space(3))) uint32_t*)l, 16, 0, 0);
}

// ======================================================================
// Split-fp16 3-pass MFMA GEMM: C = (Ahi+Alo) @ (Bhi+Blo)^T-ish
// A row-major [M][K] fp16 hi/lo; B stored TRANSPOSED [N][K] fp16 hi/lo.
// 128x128 tile, BK=32, 256 thr (4 waves 2x2), wave = 64x64 = 4x4 MFMA 16x16x32.
// LDS: seg-major cells (s=k-seg 0..3)[row 0..127] of 16B -> conflict-free
// ds_read_b128 and glds-compatible (contiguous 1KB per wave-issue).
// mode 0: scatter (B,NH,L,HD) + optional fused RoPE. mode 1: plain ldc=768.
// ======================================================================
__global__ __launch_bounds__(256)
void gemm_f16split(const _Float16* __restrict__ Ahi, const _Float16* __restrict__ Alo,
                   const _Float16* __restrict__ Bhi, const _Float16* __restrict__ Blo,
                   float* __restrict__ Cout, int mode, int doRope)
{
    __shared__ __align__(16) _Float16 sAhi[4096];
    __shared__ __align__(16) _Float16 sAlo[4096];
    __shared__ __align__(16) _Float16 sBhi[4096];
    __shared__ __align__(16) _Float16 sBlo[4096];
    const int tid = threadIdx.x;
    const int m0 = blockIdx.y * 128, n0 = blockIdx.x * 128;
    const int K = 2048;

    // staging cells: thread covers cells tid and tid+256 (16B each)
    const int c0 = tid, c1 = tid + 256;
    const int s0 = c0 >> 7, r0 = c0 & 127;
    const int s1 = c1 >> 7, r1 = c1 & 127;
    const size_t offA0 = (size_t)(m0 + r0) * K + s0 * 8;
    const size_t offA1 = (size_t)(m0 + r1) * K + s1 * 8;
    const size_t offB0 = (size_t)(n0 + r0) * K + s0 * 8;
    const size_t offB1 = (size_t)(n0 + r1) * K + s1 * 8;
    const _Float16* pAh0 = Ahi + offA0; const _Float16* pAh1 = Ahi + offA1;
    const _Float16* pAl0 = Alo + offA0; const _Float16* pAl1 = Alo + offA1;
    const _Float16* pBh0 = Bhi + offB0; const _Float16* pBh1 = Bhi + offB1;
    const _Float16* pBl0 = Blo + offB0; const _Float16* pBl1 = Blo + offB1;
    _Float16* lAh0 = &sAhi[c0 * 8]; _Float16* lAh1 = &sAhi[c1 * 8];
    _Float16* lAl0 = &sAlo[c0 * 8]; _Float16* lAl1 = &sAlo[c1 * 8];
    _Float16* lBh0 = &sBhi[c0 * 8]; _Float16* lBh1 = &sBhi[c1 * 8];
    _Float16* lBl0 = &sBlo[c0 * 8]; _Float16* lBl1 = &sBlo[c1 * 8];

    const int lane = tid & 63, quad = lane >> 4, lc = lane & 15;
    const int wv = tid >> 6, wm = wv & 1, wn = wv >> 1;
    const int fa = quad * 128 + wm * 64 + lc;   // + i*16
    const int fb = quad * 128 + wn * 64 + lc;   // + j*16

    floatx4 acc[4][4];
#pragma unroll
    for (int i = 0; i < 4; i++)
#pragma unroll
        for (int j = 0; j < 4; j++) acc[i][j] = (floatx4)0.0f;

    for (int k0 = 0; k0 < K; k0 += 32) {
        __syncthreads();
        glds16(pAh0, lAh0); glds16(pAh1, lAh1);
        glds16(pAl0, lAl0); glds16(pAl1, lAl1);
        glds16(pBh0, lBh0); glds16(pBh1, lBh1);
        glds16(pBl0, lBl0); glds16(pBl1, lBl1);
        pAh0 += 32; pAh1 += 32; pAl0 += 32; pAl1 += 32;
        pBh0 += 32; pBh1 += 32; pBl0 += 32; pBl1 += 32;
        __syncthreads();

        half8 ah[4], al[4], bh[4], bl[4];
#pragma unroll
        for (int i = 0; i < 4; i++) {
            ah[i] = *(const half8*)&sAhi[(fa + i * 16) * 8];
            al[i] = *(const half8*)&sAlo[(fa + i * 16) * 8];
        }
#pragma unroll
        for (int j = 0; j < 4; j++) {
            bh[j] = *(const half8*)&sBhi[(fb + j * 16) * 8];
            bl[j] = *(const half8*)&sBlo[(fb + j * 16) * 8];
        }
#pragma unroll
        for (int i = 0; i < 4; i++)
#pragma unroll
            for (int j = 0; j < 4; j++) {
                acc[i][j] = __builtin_amdgcn_mfma_f32_16x16x32_f16(ah[i], bh[j], acc[i][j], 0, 0, 0);
                acc[i][j] = __builtin_amdgcn_mfma_f32_16x16x32_f16(ah[i], bl[j], acc[i][j], 0, 0, 0);
                acc[i][j] = __builtin_amdgcn_mfma_f32_16x16x32_f16(al[i], bh[j], acc[i][j], 0, 0, 0);
            }
    }

    // epilogue; C/D layout: col = lane&15, row = quad*4 + reg
    float cs[4][4], sn[4][4];
    if (doRope) {
#pragma unroll
        for (int j = 0; j < 4; j++) {
            const int ii = ((j * 16 + lc) & 63) >> 1;
            const float invf = expf(-(float)ii * 0.28782313662425574f);  // ln(1e4)/32
#pragma unroll
            for (int r = 0; r < 4; r++) {
                const float ang = (float)(quad * 4 + r) * invf;  // pos%16 == row%16
                sincosf(ang, &sn[j][r], &cs[j][r]);
            }
        }
    }
    const int oddcol = lc & 1;
#pragma unroll
    for (int i = 0; i < 4; i++) {
#pragma unroll
        for (int j = 0; j < 4; j++) {
            floatx4 v = acc[i][j];
            if (doRope) {
#pragma unroll
                for (int r = 0; r < 4; r++) {
                    const float partner = __shfl_xor(v[r], 1);
                    v[r] = v[r] * cs[j][r] + partner * (oddcol ? sn[j][r] : -sn[j][r]);
                }
            }
            const int n = n0 + wn * 64 + j * 16 + lc;
            if (mode == 0) {
                const int h = (n >> 6) & 31, d = n & 63;
#pragma unroll
                for (int r = 0; r < 4; r++) {
                    const int m = m0 + wm * 64 + i * 16 + quad * 4 + r;
                    const int b = m >> 11, li = m & 2047;
                    Cout[((size_t)(b * 32 + h) * 2048 + li) * 64 + d] = v[r];
                }
            } else {
#pragma unroll
                for (int r = 0; r < 4; r++) {
                    const int m = m0 + wm * 64 + i * 16 + quad * 4 + r;
                    Cout[(size_t)m * OUT_DIM + n] = v[r];
                }
            }
        }
    }
}

// ======================================================================
// Split fp32 -> fp16 hi/lo, elementwise (float4 loads)
// ======================================================================
__global__ __launch_bounds__(256)
void split_kernel(const float* __restrict__ src, _Float16* __restrict__ hi,
                  _Float16* __restrict__ lo, int n4)
{
    const int idx = blockIdx.x * 256 + threadIdx.x;
    if (idx >= n4) return;
    const float4 x = ((const float4*)src)[idx];
    half4v h, l;
    const float xs[4] = {x.x, x.y, x.z, x.w};
#pragma unroll
    for (int e = 0; e < 4; e++) {
        const _Float16 hh = (_Float16)xs[e];
        h[e] = hh;
        l[e] = (_Float16)(xs[e] - (float)hh);
    }
    *(half4v*)&hi[(size_t)idx * 4] = h;
    *(half4v*)&lo[(size_t)idx * 4] = l;
}

// ======================================================================
// Weight transpose + split: W[K x Nw] fp32 -> BT[Nw x K] fp16 hi/lo
// ======================================================================
__global__ __launch_bounds__(256)
void wtrans_kernel(const float* __restrict__ W, _Float16* __restrict__ BThi,
                   _Float16* __restrict__ BTlo, int Nw)
{
    __shared__ float tile[32][33];
    const int t = threadIdx.x, tx = t & 31, ty = t >> 5;   // ty 0..7
    const int n0 = blockIdx.x * 32, k0 = blockIdx.y * 32;
    const int K = 2048;
#pragma unroll
    for (int r = 0; r < 4; r++)
        tile[ty + r * 8][tx] = W[(size_t)(k0 + ty + r * 8) * Nw + n0 + tx];
    __syncthreads();
#pragma unroll
    for (int r = 0; r < 4; r++) {
        const float val = tile[tx][ty + r * 8];
        const _Float16 hh = (_Float16)val;
        const size_t o = (size_t)(n0 + ty + r * 8) * K + k0 + tx;
        BThi[o] = hh;
        BTlo[o] = (_Float16)(val - (float)hh);
    }
}

// ======================================================================
// Legacy fp32 SGEMM (fallback path if workspace too small)
// ======================================================================
__global__ __launch_bounds__(256)
void sgemm_kernel(const float* __restrict__ A, const float* __restrict__ Bm,
                  float* __restrict__ C, int N, int K, int mode)
{
    __shared__ float As[16][132];
    __shared__ float Bs[16][132];
    const int tid = threadIdx.x;
    const int tx = tid & 15, ty = tid >> 4;
    const int bm = blockIdx.y * 128, bn = blockIdx.x * 128;
    float acc[8][8];
#pragma unroll
    for (int r = 0; r < 8; r++)
#pragma unroll
        for (int c = 0; c < 8; c++) acc[r][c] = 0.0f;
    const int ar = tid >> 2, ac4 = (tid & 3) * 4;
    const int br = tid >> 4, bc8 = (tid & 15) * 8;
    const float* Aptr0 = A + (size_t)(bm + ar) * K + ac4;
    const float* Aptr1 = A + (size_t)(bm + ar + 64) * K + ac4;
    const float* Bptr  = Bm + (size_t)br * N + bn + bc8;
    for (int k0 = 0; k0 < K; k0 += 16) {
        const float4 a0 = *(const float4*)(Aptr0 + k0);
        const float4 a1 = *(const float4*)(Aptr1 + k0);
        const float4 b0 = *(const float4*)(Bptr + (size_t)k0 * N);
        const float4 b1 = *(const float4*)(Bptr + (size_t)k0 * N + 4);
        As[ac4 + 0][ar] = a0.x; As[ac4 + 1][ar] = a0.y;
        As[ac4 + 2][ar] = a0.z; As[ac4 + 3][ar] = a0.w;
        As[ac4 + 0][ar + 64] = a1.x; As[ac4 + 1][ar + 64] = a1.y;
        As[ac4 + 2][ar + 64] = a1.z; As[ac4 + 3][ar + 64] = a1.w;
        *(float4*)&Bs[br][bc8]     = b0;
        *(float4*)&Bs[br][bc8 + 4] = b1;
        __syncthreads();
#pragma unroll
        for (int k = 0; k < 16; k++) {
            const float4 aa0 = *(const float4*)&As[k][ty * 8];
            const float4 aa1 = *(const float4*)&As[k][ty * 8 + 4];
            const float4 bb0 = *(const float4*)&Bs[k][tx * 8];
            const float4 bb1 = *(const float4*)&Bs[k][tx * 8 + 4];
            const float a8[8] = {aa0.x, aa0.y, aa0.z, aa0.w, aa1.x, aa1.y, aa1.z, aa1.w};
            const float b8[8] = {bb0.x, bb0.y, bb0.z, bb0.w, bb1.x, bb1.y, bb1.z, bb1.w};
#pragma unroll
            for (int r = 0; r < 8; r++)
#pragma unroll
                for (int c = 0; c < 8; c++) acc[r][c] += a8[r] * b8[c];
        }
        __syncthreads();
    }
    if (mode == 1) {
#pragma unroll
        for (int r = 0; r < 8; r++) {
            const int m = bm + ty * 8 + r;
            float* dst = C + (size_t)m * N + bn + tx * 8;
            float4 o0, o1;
            o0.x = acc[r][0]; o0.y = acc[r][1]; o0.z = acc[r][2]; o0.w = acc[r][3];
            o1.x = acc[r][4]; o1.y = acc[r][5]; o1.z = acc[r][6]; o1.w = acc[r][7];
            *(float4*)dst = o0; *(float4*)(dst + 4) = o1;
        }
    } else {
        const int ncol = bn + tx * 8;
        const int h = ncol >> 6, d0 = ncol & 63;
#pragma unroll
        for (int r = 0; r < 8; r++) {
            const int m = bm + ty * 8 + r;
            const int b = m >> 11, l = m & 2047;
            float* dst = C + ((size_t)(b * NHEADS + h) * L_SEQ + l) * HDIM + d0;
            float4 o0, o1;
            o0.x = acc[r][0]; o0.y = acc[r][1]; o0.z = acc[r][2]; o0.w = acc[r][3];
            o1.x = acc[r][4]; o1.y = acc[r][5]; o1.z = acc[r][6]; o1.w = acc[r][7];
            *(float4*)dst = o0; *(float4*)(dst + 4) = o1;
        }
    }
}

// ======================================================================
// ttt_lr sigmoid
// ======================================================================
__global__ __launch_bounds__(256)
void lr_kernel(const float* __restrict__ hidden, const float* __restrict__ wlr,
               const float* __restrict__ lr_bias, float* __restrict__ lrs)
{
    __shared__ float sRow[2048];
    __shared__ float sPart[32][9];
    const int m = blockIdx.x;
    const int t = threadIdx.x;
    const float* row = hidden + (size_t)m * C_DIM;
#pragma unroll
    for (int j = 0; j < 8; j++) sRow[t + j * 256] = row[t + j * 256];
    __syncthreads();
    const int h = t >> 3, p = t & 7;
    const float* w = wlr + (size_t)h * C_DIM;
    float s = 0.0f;
#pragma unroll 8
    for (int k = 0; k < 64; k++) {
        const int c = k * 32 + p * 4;
        const float4 a = *(const float4*)(sRow + c);
        const float4 b = *(const float4*)(w + c);
        s += a.x * b.x + a.y * b.y + a.z * b.z + a.w * b.w;
    }
    sPart[h][p] = s;
    __syncthreads();
    if (t < 32) {
        float v = 0.0f;
#pragma unroll
        for (int p2 = 0; p2 < 8; p2++) v += sPart[t][p2];
        v += lr_bias[t];
        const float sig = 1.0f / (1.0f + expf(-v));
        lrs[((size_t)(m >> 11) * NHEADS + t) * L_SEQ + (m & 2047)] = sig;
    }
}

// ======================================================================
// Standalone RoPE (fallback path only)
// ======================================================================
__global__ __launch_bounds__(256)
void rope_kernel(float* __restrict__ X, const int* __restrict__ pos_ids)
{
    const int idx = blockIdx.x * 256 + threadIdx.x;
    const int r = idx >> 5, ii = idx & 31;
    const int l = r & 2047;
    const int b = r >> 16;
    const int p = pos_ids[(b << 11) + l] & 15;
    const float angle = (float)p * expf(-(float)ii * 0.28782313662425574f);
    float s, c;
    sincosf(angle, &s, &c);
    float2* ptr = (float2*)(X + (size_t)r * HDIM + ii * 2);
    const float2 x = *ptr;
    float2 o;
    o.x = x.x * c - x.y * s;
    o.y = x.y * c + x.x * s;
    *ptr = o;
}

// ======================================================================
// TTT scan: one block per (b,h), state in LDS, out over XV
// ======================================================================
__global__ __launch_bounds__(256)
void scan_kernel(const float* __restrict__ XQ, const float* __restrict__ XK,
                 float* __restrict__ XVo, const float* __restrict__ LRS,
                 const float* __restrict__ W1i, const float* __restrict__ b1i,
                 const float* __restrict__ lt, const float* __restrict__ lnw,
                 const float* __restrict__ lnb)
{
    __shared__ float sW1[64][68];
    __shared__ float sXq[16][68], sXk[16][68], sXv[16][68], sGrad[16][68];
    __shared__ float sCoeff[16][16];
    __shared__ float sB1[64], sGamma[64], sBeta[64];
    __shared__ float sEta[16], sTok[16];

    const int bh = blockIdx.x;
    const int h = bh & 31;
    const int t = threadIdx.x;
#pragma unroll
    for (int r = 0; r < 16; r++) {
        const int idx = t + r * 256;
        sW1[idx >> 6][idx & 63] = W1i[h * 4096 + idx];
    }
    if (t < 64) {
        sB1[t] = b1i[h * 64 + t];
        sGamma[t] = lnw[h * 64 + t];
        sBeta[t] = lnb[h * 64 + t];
    }
    if (t < 16) sTok[t] = fmaxf(1.0f / (float)(t + 1) + lt[t], 0.0f);

    const size_t base = (size_t)bh * L_SEQ * HDIM;
    const float* xq_g = XQ + base;
    const float* xk_g = XK + base;
    float* xv_g = XVo + base;
    const float* lr_g = LRS + (size_t)bh * L_SEQ;
    const int i = t >> 4, lane = t & 15, d0 = lane * 4;
    __syncthreads();

    for (int n = 0; n < NMINI; n++) {
        {
            const int off = n * (MBS_ * HDIM) + t * 4;
            const float4 q = *(const float4*)(xq_g + off);
            const float4 kk = *(const float4*)(xk_g + off);
            const float4 vv = *(const float4*)(xv_g + off);
            *(float4*)&sXq[i][d0] = q;
            *(float4*)&sXk[i][d0] = kk;
            *(float4*)&sXv[i][d0] = vv;
            if (t < 16) sEta[t] = lr_g[n * MBS_ + t] * (1.0f / 64.0f);
        }
        __syncthreads();

        float z[4] = {0, 0, 0, 0}, xqw[4] = {0, 0, 0, 0};
#pragma unroll
        for (int k4 = 0; k4 < 16; k4++) {
            const float4 xk4 = *(const float4*)&sXk[i][k4 * 4];
            const float4 xq4 = *(const float4*)&sXq[i][k4 * 4];
            const float kx[4] = {xk4.x, xk4.y, xk4.z, xk4.w};
            const float qx[4] = {xq4.x, xq4.y, xq4.z, xq4.w};
#pragma unroll
            for (int kk = 0; kk < 4; kk++) {
                const float4 w = *(const float4*)&sW1[k4 * 4 + kk][d0];
                z[0] += kx[kk] * w.x; z[1] += kx[kk] * w.y;
                z[2] += kx[kk] * w.z; z[3] += kx[kk] * w.w;
                xqw[0] += qx[kk] * w.x; xqw[1] += qx[kk] * w.y;
                xqw[2] += qx[kk] * w.z; xqw[3] += qx[kk] * w.w;
            }
        }
#pragma unroll
        for (int c = 0; c < 4; c++) z[c] += sB1[d0 + c];

        float s1 = z[0] + z[1] + z[2] + z[3];
        float s2 = z[0] * z[0] + z[1] * z[1] + z[2] * z[2] + z[3] * z[3];
#pragma unroll
        for (int o = 1; o < 16; o <<= 1) { s1 += __shfl_xor(s1, o); s2 += __shfl_xor(s2, o); }
        const float mu = s1 * (1.0f / 64.0f);
        const float var = s2 * (1.0f / 64.0f) - mu * mu;
        const float rstd = rsqrtf(var + EPS_);
        float gg[4], xh[4];
        float sg = 0.0f, sgx = 0.0f;
#pragma unroll
        for (int c = 0; c < 4; c++) {
            xh[c] = (z[c] - mu) * rstd;
            const float ga = sGamma[d0 + c];
            const float y = ga * xh[c] + sBeta[d0 + c];
            const float tgt = sXv[i][d0 + c] - sXk[i][d0 + c];
            gg[c] = (y - tgt) * ga;
            sg += gg[c];
            sgx += gg[c] * xh[c];
        }
#pragma unroll
        for (int o = 1; o < 16; o <<= 1) { sg += __shfl_xor(sg, o); sgx += __shfl_xor(sgx, o); }
        {
            const float sc = rstd * (1.0f / 64.0f);
            float4 gr;
            gr.x = (64.0f * gg[0] - sg - xh[0] * sgx) * sc;
            gr.y = (64.0f * gg[1] - sg - xh[1] * sgx) * sc;
            gr.z = (64.0f * gg[2] - sg - xh[2] * sgx) * sc;
            gr.w = (64.0f * gg[3] - sg - xh[3] * sgx) * sc;
            *(float4*)&sGrad[i][d0] = gr;
        }
        {
            float a = 0.0f;
#pragma unroll
            for (int k4 = 0; k4 < 16; k4++) {
                const float4 qa = *(const float4*)&sXq[i][k4 * 4];
                const float4 kb = *(const float4*)&sXk[lane][k4 * 4];
                a += qa.x * kb.x + qa.y * kb.y + qa.z * kb.z + qa.w * kb.w;
            }
            sCoeff[i][lane] = (lane <= i) ? sTok[i] * sEta[lane] * (a + 1.0f) : 0.0f;
        }
        __syncthreads();

        float zb[4];
#pragma unroll
        for (int c = 0; c < 4; c++) zb[c] = xqw[c] + sB1[d0 + c];
#pragma unroll
        for (int j = 0; j < 16; j++) {
            const float cf = sCoeff[i][j];
            const float4 g4 = *(const float4*)&sGrad[j][d0];
            zb[0] -= cf * g4.x; zb[1] -= cf * g4.y;
            zb[2] -= cf * g4.z; zb[3] -= cf * g4.w;
        }
        float u1 = zb[0] + zb[1] + zb[2] + zb[3];
        float u2 = zb[0] * zb[0] + zb[1] * zb[1] + zb[2] * zb[2] + zb[3] * zb[3];
#pragma unroll
        for (int o = 1; o < 16; o <<= 1) { u1 += __shfl_xor(u1, o); u2 += __shfl_xor(u2, o); }
        const float mu2 = u1 * (1.0f / 64.0f);
        const float var2 = u2 * (1.0f / 64.0f) - mu2 * mu2;
        const float rstd2 = rsqrtf(var2 + EPS_);
        {
            float4 outv;
            outv.x = sXq[i][d0 + 0] + sGamma[d0 + 0] * ((zb[0] - mu2) * rstd2) + sBeta[d0 + 0];
            outv.y = sXq[i][d0 + 1] + sGamma[d0 + 1] * ((zb[1] - mu2) * rstd2) + sBeta[d0 + 1];
            outv.z = sXq[i][d0 + 2] + sGamma[d0 + 2] * ((zb[2] - mu2) * rstd2) + sBeta[d0 + 2];
            outv.w = sXq[i][d0 + 3] + sGamma[d0 + 3] * ((zb[3] - mu2) * rstd2) + sBeta[d0 + 3];
            *(float4*)(xv_g + n * (MBS_ * HDIM) + t * 4) = outv;
        }
        __syncthreads();

        {
            const float T15 = sTok[15];
            const int d = t >> 2, e0 = (t & 3) * 16;
            float acc[16];
#pragma unroll
            for (int e = 0; e < 16; e++) acc[e] = 0.0f;
#pragma unroll
            for (int j = 0; j < 16; j++) {
                const float lj = sEta[j] * sXk[j][d];
                const float* gr = &sGrad[j][e0];
#pragma unroll
                for (int e = 0; e < 16; e++) acc[e] += lj * gr[e];
            }
            float* wr = &sW1[d][e0];
#pragma unroll
            for (int e = 0; e < 16; e++) wr[e] -= T15 * acc[e];
            if (t < 64) {
                float s = 0.0f;
#pragma unroll
                for (int j = 0; j < 16; j++) s += sEta[j] * sGrad[j][t];
                sB1[t] -= T15 * s;
            }
        }
        __syncthreads();
    }
}

// ======================================================================
// post-norm; mode 0: write fp32 XN; mode 1: write fp16 hi/lo splits
// ======================================================================
__global__ __launch_bounds__(256)
void postln_kernel(const float* __restrict__ Ob, const float* __restrict__ pnw,
                   const float* __restrict__ pnb, float* __restrict__ XN,
                   _Float16* __restrict__ XNhi, _Float16* __restrict__ XNlo, int mode)
{
    const int m = blockIdx.x;
    const int b = m >> 11, l = m & 2047;
    const int t = threadIdx.x;
    float v[8];
    float s1 = 0.0f, s2 = 0.0f;
    const float* bas = Ob + (size_t)b * NHEADS * L_SEQ * HDIM + (size_t)l * HDIM;
#pragma unroll
    for (int j = 0; j < 8; j++) {
        const int c = t + j * 256;
        const int hh = c >> 6, d = c & 63;
        const float x = bas[(size_t)hh * (L_SEQ * HDIM) + d];
        v[j] = x; s1 += x; s2 += x * x;
    }
#pragma unroll
    for (int o = 1; o < 64; o <<= 1) { s1 += __shfl_xor(s1, o); s2 += __shfl_xor(s2, o); }
    __shared__ float r1[4], r2[4];
    const int w = t >> 6;
    if ((t & 63) == 0) { r1[w] = s1; r2[w] = s2; }
    __syncthreads();
    s1 = r1[0] + r1[1] + r1[2] + r1[3];
    s2 = r2[0] + r2[1] + r2[2] + r2[3];
    const float mu = s1 * (1.0f / 2048.0f);
    const float var = s2 * (1.0f / 2048.0f) - mu * mu;
    const float rstd = rsqrtf(var + EPS_);
#pragma unroll
    for (int j = 0; j < 8; j++) {
        const int c = t + j * 256;
        const float val = (v[j] - mu) * rstd * pnw[c] + pnb[c];
        if (mode == 0) {
            XN[(size_t)m * C_DIM + c] = val;
        } else {
            const _Float16 hh = (_Float16)val;
            XNhi[(size_t)m * C_DIM + c] = hh;
            XNlo[(size_t)m * C_DIM + c] = (_Float16)(val - (float)hh);
        }
    }
}

// ======================================================================
extern "C" void kernel_launch(void* const* d_in, const int* in_sizes, int n_in,
                              void* d_out, int out_size, void* d_ws, size_t ws_size,
                              hipStream_t stream)
{
    (void)in_sizes; (void)n_in; (void)out_size;
    const float* hidden  = (const float*)d_in[0];
    const int*   pos_ids = (const int*)d_in[1];
    const float* Wq      = (const float*)d_in[2];
    const float* Wk      = (const float*)d_in[3];
    const float* Wv      = (const float*)d_in[4];
    const float* Wo      = (const float*)d_in[5];
    const float* W1      = (const float*)d_in[6];
    const float* b1      = (const float*)d_in[7];
    const float* wlr     = (const float*)d_in[8];
    const float* lr_bias = (const float*)d_in[9];
    const float* lt      = (const float*)d_in[10];
    const float* lnw     = (const float*)d_in[11];
    const float* lnb     = (const float*)d_in[12];
    const float* pnw     = (const float*)d_in[13];
    const float* pnb     = (const float*)d_in[14];

    const size_t TEN = (size_t)B_DIM * NHEADS * L_SEQ * HDIM;  // 16777216
    float* XQ  = (float*)d_ws;
    float* XK  = XQ + TEN;
    float* XVo = XK + TEN;
    float* LRS = XVo + TEN;
    const dim3 blk(256);

    // Fast path workspace: 3*TEN*4 + 1MB + A-splits 2*TEN*2 + BT splits 2*4M*2
    const size_t FAST_WS = 3 * TEN * 4 + 1048576 + 2 * TEN * 2 + 2 * (size_t)4194304 * 2;
    if (ws_size >= FAST_WS) {
        char* byt = (char*)d_ws;
        _Float16* Ahi  = (_Float16*)(byt + 3 * TEN * 4 + 1048576);
        _Float16* Alo  = Ahi + TEN;
        _Float16* BThi = Alo + TEN;
        _Float16* BTlo = BThi + 4194304;
        _Float16* XNhi = Ahi;     // reuse after GEMMs consume A-splits
        _Float16* XNlo = Alo;
        _Float16* WThi = BThi;    // reuse after QKV GEMMs
        _Float16* WTlo = BTlo;

        split_kernel<<<dim3(16384), blk, 0, stream>>>(hidden, Ahi, Alo, (int)(TEN / 4));
        lr_kernel<<<dim3(B_DIM * L_SEQ), blk, 0, stream>>>(hidden, wlr, lr_bias, LRS);

        const float* Wmats[3] = {Wq, Wk, Wv};
        float* outs[3] = {XQ, XK, XVo};
        for (int p = 0; p < 3; p++) {
            wtrans_kernel<<<dim3(64, 64), blk, 0, stream>>>(Wmats[p], BThi, BTlo, 2048);
            gemm_f16split<<<dim3(16, 64), blk, 0, stream>>>(Ahi, Alo, BThi, BTlo,
                                                            outs[p], 0, (p < 2) ? 1 : 0);
        }
        scan_kernel<<<dim3(B_DIM * NHEADS), blk, 0, stream>>>(XQ, XK, XVo, LRS,
                                                              W1, b1, lt, lnw, lnb);
        postln_kernel<<<dim3(B_DIM * L_SEQ), blk, 0, stream>>>(XVo, pnw, pnb,
                                                               (float*)nullptr, XNhi, XNlo, 1);
        wtrans_kernel<<<dim3(24, 64), blk, 0, stream>>>(Wo, WThi, WTlo, OUT_DIM);
        gemm_f16split<<<dim3(6, 64), blk, 0, stream>>>(XNhi, XNlo, WThi, WTlo,
                                                       (float*)d_out, 1, 0);
    } else {
        // Fallback: proven R1 fp32 path (202 MB workspace)
        float* XN = XQ;
        sgemm_kernel<<<dim3(16, 64), blk, 0, stream>>>(hidden, Wq, XQ,  C_DIM, C_DIM, 0);
        sgemm_kernel<<<dim3(16, 64), blk, 0, stream>>>(hidden, Wk, XK,  C_DIM, C_DIM, 0);
        sgemm_kernel<<<dim3(16, 64), blk, 0, stream>>>(hidden, Wv, XVo, C_DIM, C_DIM, 0);
        lr_kernel<<<dim3(B_DIM * L_SEQ), blk, 0, stream>>>(hidden, wlr, lr_bias, LRS);
        rope_kernel<<<dim3(32768), blk, 0, stream>>>(XQ, pos_ids);
        rope_kernel<<<dim3(32768), blk, 0, stream>>>(XK, pos_ids);
        scan_kernel<<<dim3(B_DIM * NHEADS), blk, 0, stream>>>(XQ, XK, XVo, LRS,
                                                              W1, b1, lt, lnw, lnb);
        postln_kernel<<<dim3(B_DIM * L_SEQ), blk, 0, stream>>>(XVo, pnw, pnb, XN,
                                                               (_Float16*)nullptr,
                                                               (_Float16*)nullptr, 0);
        sgemm_kernel<<<dim3(6, 64), blk, 0, stream>>>(XN, Wo, (float*)d_out, OUT_DIM, C_DIM, 1);
    }
    (void)pos_ids;
}

// Round 3
// 1695.715 us; speedup vs baseline: 2.2680x; 2.1992x over previous
//
#include <hip/hip_runtime.h>
#include <cstddef>
#include <cstdint>

// Problem constants
#define B_DIM   4
#define L_SEQ   2048
#define C_DIM   2048
#define OUT_DIM 768
#define NHEADS  32
#define HDIM    64
#define MBS_    16
#define NMINI   128
#define EPS_    1e-6f

typedef _Float16 half8 __attribute__((ext_vector_type(8)));
typedef float floatx4 __attribute__((ext_vector_type(4)));

__device__ __forceinline__ void glds16(const void* g, void* l) {
    __builtin_amdgcn_global_load_lds(
        (const __attribute__((address_space(1))) uint32_t*)g,
        (__attribute__((address_space(3))) uint32_t*)l, 16, 0, 0);
}

// ======================================================================
// MFMA GEMM, A = fp32 row-major [M][K=2048] split to fp16 hi/lo ON THE FLY,
// B = pre-split fp16 hi/lo, TRANSPOSED [N][K].  3-pass split-fp16 (fp32-
// accurate): C = Ahi*Bhi + Ahi*Blo + Alo*Bhi.
// 128x128 tile, BK=32, 256 thr (4 waves 2x2), 4x4 MFMA 16x16x32 per wave.
// LDS cells (16B) row-major with XOR swizzle: A seg^=(row&7) [8 segs/row],
// B seg^=((row>>1)&3) [4 segs/row] -> conflict-free ds_read_b128 AND
// contiguous-per-row global_load_lds.
// mode 0: scatter to (B,NH,L,HD), optional fused RoPE (pos = m%16).
// mode 1: plain row-major C, ldc = OUT_DIM.
// ======================================================================
__global__ __launch_bounds__(256)
void gemm_af32(const float* __restrict__ A,
               const _Float16* __restrict__ Bhi, const _Float16* __restrict__ Blo,
               float* __restrict__ Cout, int mode, int doRope)
{
    __shared__ __align__(16) float    sA[4096];     // 128 rows x 32 k (16 KB)
    __shared__ __align__(16) _Float16 sBhi[4096];   // 128 rows x 32 k (8 KB)
    __shared__ __align__(16) _Float16 sBlo[4096];
    const int tid = threadIdx.x;
    const int m0 = blockIdx.y * 128, n0 = blockIdx.x * 128;
    const int K = 2048;

    // ---- staging maps (glds16: lds dst = linear cell = issue*256 + tid) ----
    size_t gA[4]; float* lA[4];
#pragma unroll
    for (int I = 0; I < 4; I++) {
        const int c = I * 256 + tid;
        const int row = c >> 3, seg = (c & 7) ^ (row & 7);
        gA[I] = (size_t)(m0 + row) * K + seg * 4;
        lA[I] = &sA[c * 4];
    }
    size_t gB[2]; _Float16 *lBh[2], *lBl[2];
#pragma unroll
    for (int I = 0; I < 2; I++) {
        const int c = I * 256 + tid;
        const int row = c >> 2, seg = (c & 3) ^ ((row >> 1) & 3);
        gB[I] = (size_t)(n0 + row) * K + seg * 8;
        lBh[I] = &sBhi[c * 8];
        lBl[I] = &sBlo[c * 8];
    }

    // ---- fragment maps ----
    const int lane = tid & 63, quad = lane >> 4, lc = lane & 15;
    const int wv = tid >> 6, wm = wv & 1, wn = wv >> 1;
    int offA0[4], offA1[4], offB[4];
#pragma unroll
    for (int i = 0; i < 4; i++) {
        const int rA = wm * 64 + i * 16 + lc;
        offA0[i] = (rA * 8 + ((2 * quad)     ^ (rA & 7))) * 4;
        offA1[i] = (rA * 8 + ((2 * quad + 1) ^ (rA & 7))) * 4;
    }
#pragma unroll
    for (int j = 0; j < 4; j++) {
        const int rB = wn * 64 + j * 16 + lc;
        offB[j] = (rB * 4 + (quad ^ ((rB >> 1) & 3))) * 8;
    }

    floatx4 acc[4][4];
#pragma unroll
    for (int i = 0; i < 4; i++)
#pragma unroll
        for (int j = 0; j < 4; j++) acc[i][j] = (floatx4)0.0f;

    for (int k0 = 0; k0 < K; k0 += 32) {
        __syncthreads();
#pragma unroll
        for (int I = 0; I < 4; I++) glds16(A + gA[I] + k0, lA[I]);
#pragma unroll
        for (int I = 0; I < 2; I++) {
            glds16(Bhi + gB[I] + k0, lBh[I]);
            glds16(Blo + gB[I] + k0, lBl[I]);
        }
        __syncthreads();

        half8 ah[4], al[4], bh[4], bl[4];
#pragma unroll
        for (int i = 0; i < 4; i++) {
            const float4 va = *(const float4*)&sA[offA0[i]];
            const float4 vb = *(const float4*)&sA[offA1[i]];
            const float af[8] = {va.x, va.y, va.z, va.w, vb.x, vb.y, vb.z, vb.w};
#pragma unroll
            for (int t = 0; t < 8; t++) {
                const _Float16 hh = (_Float16)af[t];
                ah[i][t] = hh;
                al[i][t] = (_Float16)(af[t] - (float)hh);
            }
        }
#pragma unroll
        for (int j = 0; j < 4; j++) {
            bh[j] = *(const half8*)&sBhi[offB[j]];
            bl[j] = *(const half8*)&sBlo[offB[j]];
        }
#pragma unroll
        for (int i = 0; i < 4; i++)
#pragma unroll
            for (int j = 0; j < 4; j++) {
                acc[i][j] = __builtin_amdgcn_mfma_f32_16x16x32_f16(ah[i], bh[j], acc[i][j], 0, 0, 0);
                acc[i][j] = __builtin_amdgcn_mfma_f32_16x16x32_f16(ah[i], bl[j], acc[i][j], 0, 0, 0);
                acc[i][j] = __builtin_amdgcn_mfma_f32_16x16x32_f16(al[i], bh[j], acc[i][j], 0, 0, 0);
            }
    }

    // ---- epilogue; C/D layout: col = lane&15, row = quad*4 + reg ----
    float cs[4][4], sn[4][4];
    if (doRope) {
#pragma unroll
        for (int j = 0; j < 4; j++) {
            const int ii = ((j * 16 + lc) & 63) >> 1;     // head-dim pair index
            const float invf = expf(-(float)ii * 0.28782313662425574f); // ln(1e4)/32
#pragma unroll
            for (int r = 0; r < 4; r++) {
                const float ang = (float)(quad * 4 + r) * invf;  // pos%16 == m%16
                sincosf(ang, &sn[j][r], &cs[j][r]);
            }
        }
    }
    const int oddcol = lc & 1;
#pragma unroll
    for (int i = 0; i < 4; i++) {
#pragma unroll
        for (int j = 0; j < 4; j++) {
            floatx4 v = acc[i][j];
            if (doRope) {
#pragma unroll
                for (int r = 0; r < 4; r++) {
                    const float partner = __shfl_xor(v[r], 1);
                    v[r] = v[r] * cs[j][r] + partner * (oddcol ? sn[j][r] : -sn[j][r]);
                }
            }
            const int n = n0 + wn * 64 + j * 16 + lc;
            if (mode == 0) {
                const int h = (n >> 6) & 31, d = n & 63;
#pragma unroll
                for (int r = 0; r < 4; r++) {
                    const int m = m0 + wm * 64 + i * 16 + quad * 4 + r;
                    const int b = m >> 11, li = m & 2047;
                    Cout[((size_t)(b * 32 + h) * 2048 + li) * 64 + d] = v[r];
                }
            } else {
#pragma unroll
                for (int r = 0; r < 4; r++) {
                    const int m = m0 + wm * 64 + i * 16 + quad * 4 + r;
                    Cout[(size_t)m * OUT_DIM + n] = v[r];
                }
            }
        }
    }
}

// ======================================================================
// Weight transpose + split: W[K x Nw] fp32 -> BT[Nw x K] fp16 hi/lo
// ======================================================================
__global__ __launch_bounds__(256)
void wtrans_kernel(const float* __restrict__ W, _Float16* __restrict__ BThi,
                   _Float16* __restrict__ BTlo, int Nw)
{
    __shared__ float tile[32][33];
    const int t = threadIdx.x, tx = t & 31, ty = t >> 5;   // ty 0..7
    const int n0 = blockIdx.x * 32, k0 = blockIdx.y * 32;
    const int K = 2048;
#pragma unroll
    for (int r = 0; r < 4; r++)
        tile[ty + r * 8][tx] = W[(size_t)(k0 + ty + r * 8) * Nw + n0 + tx];
    __syncthreads();
#pragma unroll
    for (int r = 0; r < 4; r++) {
        const float val = tile[tx][ty + r * 8];
        const _Float16 hh = (_Float16)val;
        const size_t o = (size_t)(n0 + ty + r * 8) * K + k0 + tx;
        BThi[o] = hh;
        BTlo[o] = (_Float16)(val - (float)hh);
    }
}

// ======================================================================
// Legacy fp32 SGEMM (fallback only)
// ======================================================================
__global__ __launch_bounds__(256)
void sgemm_kernel(const float* __restrict__ A, const float* __restrict__ Bm,
                  float* __restrict__ C, int N, int K, int mode)
{
    __shared__ float As[16][132];
    __shared__ float Bs[16][132];
    const int tid = threadIdx.x;
    const int tx = tid & 15, ty = tid >> 4;
    const int bm = blockIdx.y * 128, bn = blockIdx.x * 128;
    float acc[8][8];
#pragma unroll
    for (int r = 0; r < 8; r++)
#pragma unroll
        for (int c = 0; c < 8; c++) acc[r][c] = 0.0f;
    const int ar = tid >> 2, ac4 = (tid & 3) * 4;
    const int br = tid >> 4, bc8 = (tid & 15) * 8;
    const float* Aptr0 = A + (size_t)(bm + ar) * K + ac4;
    const float* Aptr1 = A + (size_t)(bm + ar + 64) * K + ac4;
    const float* Bptr  = Bm + (size_t)br * N + bn + bc8;
    for (int k0 = 0; k0 < K; k0 += 16) {
        const float4 a0 = *(const float4*)(Aptr0 + k0);
        const float4 a1 = *(const float4*)(Aptr1 + k0);
        const float4 b0 = *(const float4*)(Bptr + (size_t)k0 * N);
        const float4 b1 = *(const float4*)(Bptr + (size_t)k0 * N + 4);
        As[ac4 + 0][ar] = a0.x; As[ac4 + 1][ar] = a0.y;
        As[ac4 + 2][ar] = a0.z; As[ac4 + 3][ar] = a0.w;
        As[ac4 + 0][ar + 64] = a1.x; As[ac4 + 1][ar + 64] = a1.y;
        As[ac4 + 2][ar + 64] = a1.z; As[ac4 + 3][ar + 64] = a1.w;
        *(float4*)&Bs[br][bc8]     = b0;
        *(float4*)&Bs[br][bc8 + 4] = b1;
        __syncthreads();
#pragma unroll
        for (int k = 0; k < 16; k++) {
            const float4 aa0 = *(const float4*)&As[k][ty * 8];
            const float4 aa1 = *(const float4*)&As[k][ty * 8 + 4];
            const float4 bb0 = *(const float4*)&Bs[k][tx * 8];
            const float4 bb1 = *(const float4*)&Bs[k][tx * 8 + 4];
            const float a8[8] = {aa0.x, aa0.y, aa0.z, aa0.w, aa1.x, aa1.y, aa1.z, aa1.w};
            const float b8[8] = {bb0.x, bb0.y, bb0.z, bb0.w, bb1.x, bb1.y, bb1.z, bb1.w};
#pragma unroll
            for (int r = 0; r < 8; r++)
#pragma unroll
                for (int c = 0; c < 8; c++) acc[r][c] += a8[r] * b8[c];
        }
        __syncthreads();
    }
    if (mode == 1) {
#pragma unroll
        for (int r = 0; r < 8; r++) {
            const int m = bm + ty * 8 + r;
            float* dst = C + (size_t)m * N + bn + tx * 8;
            float4 o0, o1;
            o0.x = acc[r][0]; o0.y = acc[r][1]; o0.z = acc[r][2]; o0.w = acc[r][3];
            o1.x = acc[r][4]; o1.y = acc[r][5]; o1.z = acc[r][6]; o1.w = acc[r][7];
            *(float4*)dst = o0; *(float4*)(dst + 4) = o1;
        }
    } else {
        const int ncol = bn + tx * 8;
        const int h = ncol >> 6, d0 = ncol & 63;
#pragma unroll
        for (int r = 0; r < 8; r++) {
            const int m = bm + ty * 8 + r;
            const int b = m >> 11, l = m & 2047;
            float* dst = C + ((size_t)(b * NHEADS + h) * L_SEQ + l) * HDIM + d0;
            float4 o0, o1;
            o0.x = acc[r][0]; o0.y = acc[r][1]; o0.z = acc[r][2]; o0.w = acc[r][3];
            o1.x = acc[r][4]; o1.y = acc[r][5]; o1.z = acc[r][6]; o1.w = acc[r][7];
            *(float4*)dst = o0; *(float4*)(dst + 4) = o1;
        }
    }
}

// ======================================================================
// ttt_lr sigmoid
// ======================================================================
__global__ __launch_bounds__(256)
void lr_kernel(const float* __restrict__ hidden, const float* __restrict__ wlr,
               const float* __restrict__ lr_bias, float* __restrict__ lrs)
{
    __shared__ float sRow[2048];
    __shared__ float sPart[32][9];
    const int m = blockIdx.x;
    const int t = threadIdx.x;
    const float* row = hidden + (size_t)m * C_DIM;
#pragma unroll
    for (int j = 0; j < 8; j++) sRow[t + j * 256] = row[t + j * 256];
    __syncthreads();
    const int h = t >> 3, p = t & 7;
    const float* w = wlr + (size_t)h * C_DIM;
    float s = 0.0f;
#pragma unroll 8
    for (int k = 0; k < 64; k++) {
        const int c = k * 32 + p * 4;
        const float4 a = *(const float4*)(sRow + c);
        const float4 b = *(const float4*)(w + c);
        s += a.x * b.x + a.y * b.y + a.z * b.z + a.w * b.w;
    }
    sPart[h][p] = s;
    __syncthreads();
    if (t < 32) {
        float v = 0.0f;
#pragma unroll
        for (int p2 = 0; p2 < 8; p2++) v += sPart[t][p2];
        v += lr_bias[t];
        const float sig = 1.0f / (1.0f + expf(-v));
        lrs[((size_t)(m >> 11) * NHEADS + t) * L_SEQ + (m & 2047)] = sig;
    }
}

// ======================================================================
// Standalone RoPE (fallback only)
// ======================================================================
__global__ __launch_bounds__(256)
void rope_kernel(float* __restrict__ X, const int* __restrict__ pos_ids)
{
    const int idx = blockIdx.x * 256 + threadIdx.x;
    const int r = idx >> 5, ii = idx & 31;
    const int l = r & 2047;
    const int b = r >> 16;
    const int p = pos_ids[(b << 11) + l] & 15;
    const float angle = (float)p * expf(-(float)ii * 0.28782313662425574f);
    float s, c;
    sincosf(angle, &s, &c);
    float2* ptr = (float2*)(X + (size_t)r * HDIM + ii * 2);
    const float2 x = *ptr;
    float2 o;
    o.x = x.x * c - x.y * s;
    o.y = x.y * c + x.x * s;
    *ptr = o;
}

// ======================================================================
// TTT scan: one block per (b,h), state in LDS, out over XV
// ======================================================================
__global__ __launch_bounds__(256)
void scan_kernel(const float* __restrict__ XQ, const float* __restrict__ XK,
                 float* __restrict__ XVo, const float* __restrict__ LRS,
                 const float* __restrict__ W1i, const float* __restrict__ b1i,
                 const float* __restrict__ lt, const float* __restrict__ lnw,
                 const float* __restrict__ lnb)
{
    __shared__ float sW1[64][68];
    __shared__ float sXq[16][68], sXk[16][68], sXv[16][68], sGrad[16][68];
    __shared__ float sCoeff[16][16];
    __shared__ float sB1[64], sGamma[64], sBeta[64];
    __shared__ float sEta[16], sTok[16];

    const int bh = blockIdx.x;
    const int h = bh & 31;
    const int t = threadIdx.x;
#pragma unroll
    for (int r = 0; r < 16; r++) {
        const int idx = t + r * 256;
        sW1[idx >> 6][idx & 63] = W1i[h * 4096 + idx];
    }
    if (t < 64) {
        sB1[t] = b1i[h * 64 + t];
        sGamma[t] = lnw[h * 64 + t];
        sBeta[t] = lnb[h * 64 + t];
    }
    if (t < 16) sTok[t] = fmaxf(1.0f / (float)(t + 1) + lt[t], 0.0f);

    const size_t base = (size_t)bh * L_SEQ * HDIM;
    const float* xq_g = XQ + base;
    const float* xk_g = XK + base;
    float* xv_g = XVo + base;
    const float* lr_g = LRS + (size_t)bh * L_SEQ;
    const int i = t >> 4, lane = t & 15, d0 = lane * 4;
    __syncthreads();

    for (int n = 0; n < NMINI; n++) {
        {
            const int off = n * (MBS_ * HDIM) + t * 4;
            const float4 q = *(const float4*)(xq_g + off);
            const float4 kk = *(const float4*)(xk_g + off);
            const float4 vv = *(const float4*)(xv_g + off);
            *(float4*)&sXq[i][d0] = q;
            *(float4*)&sXk[i][d0] = kk;
            *(float4*)&sXv[i][d0] = vv;
            if (t < 16) sEta[t] = lr_g[n * MBS_ + t] * (1.0f / 64.0f);
        }
        __syncthreads();

        float z[4] = {0, 0, 0, 0}, xqw[4] = {0, 0, 0, 0};
#pragma unroll
        for (int k4 = 0; k4 < 16; k4++) {
            const float4 xk4 = *(const float4*)&sXk[i][k4 * 4];
            const float4 xq4 = *(const float4*)&sXq[i][k4 * 4];
            const float kx[4] = {xk4.x, xk4.y, xk4.z, xk4.w};
            const float qx[4] = {xq4.x, xq4.y, xq4.z, xq4.w};
#pragma unroll
            for (int kk = 0; kk < 4; kk++) {
                const float4 w = *(const float4*)&sW1[k4 * 4 + kk][d0];
                z[0] += kx[kk] * w.x; z[1] += kx[kk] * w.y;
                z[2] += kx[kk] * w.z; z[3] += kx[kk] * w.w;
                xqw[0] += qx[kk] * w.x; xqw[1] += qx[kk] * w.y;
                xqw[2] += qx[kk] * w.z; xqw[3] += qx[kk] * w.w;
            }
        }
#pragma unroll
        for (int c = 0; c < 4; c++) z[c] += sB1[d0 + c];

        float s1 = z[0] + z[1] + z[2] + z[3];
        float s2 = z[0] * z[0] + z[1] * z[1] + z[2] * z[2] + z[3] * z[3];
#pragma unroll
        for (int o = 1; o < 16; o <<= 1) { s1 += __shfl_xor(s1, o); s2 += __shfl_xor(s2, o); }
        const float mu = s1 * (1.0f / 64.0f);
        const float var = s2 * (1.0f / 64.0f) - mu * mu;
        const float rstd = rsqrtf(var + EPS_);
        float gg[4], xh[4];
        float sg = 0.0f, sgx = 0.0f;
#pragma unroll
        for (int c = 0; c < 4; c++) {
            xh[c] = (z[c] - mu) * rstd;
            const float ga = sGamma[d0 + c];
            const float y = ga * xh[c] + sBeta[d0 + c];
            const float tgt = sXv[i][d0 + c] - sXk[i][d0 + c];
            gg[c] = (y - tgt) * ga;
            sg += gg[c];
            sgx += gg[c] * xh[c];
        }
#pragma unroll
        for (int o = 1; o < 16; o <<= 1) { sg += __shfl_xor(sg, o); sgx += __shfl_xor(sgx, o); }
        {
            const float sc = rstd * (1.0f / 64.0f);
            float4 gr;
            gr.x = (64.0f * gg[0] - sg - xh[0] * sgx) * sc;
            gr.y = (64.0f * gg[1] - sg - xh[1] * sgx) * sc;
            gr.z = (64.0f * gg[2] - sg - xh[2] * sgx) * sc;
            gr.w = (64.0f * gg[3] - sg - xh[3] * sgx) * sc;
            *(float4*)&sGrad[i][d0] = gr;
        }
        {
            float a = 0.0f;
#pragma unroll
            for (int k4 = 0; k4 < 16; k4++) {
                const float4 qa = *(const float4*)&sXq[i][k4 * 4];
                const float4 kb = *(const float4*)&sXk[lane][k4 * 4];
                a += qa.x * kb.x + qa.y * kb.y + qa.z * kb.z + qa.w * kb.w;
            }
            sCoeff[i][lane] = (lane <= i) ? sTok[i] * sEta[lane] * (a + 1.0f) : 0.0f;
        }
        __syncthreads();

        float zb[4];
#pragma unroll
        for (int c = 0; c < 4; c++) zb[c] = xqw[c] + sB1[d0 + c];
#pragma unroll
        for (int j = 0; j < 16; j++) {
            const float cf = sCoeff[i][j];
            const float4 g4 = *(const float4*)&sGrad[j][d0];
            zb[0] -= cf * g4.x; zb[1] -= cf * g4.y;
            zb[2] -= cf * g4.z; zb[3] -= cf * g4.w;
        }
        float u1 = zb[0] + zb[1] + zb[2] + zb[3];
        float u2 = zb[0] * zb[0] + zb[1] * zb[1] + zb[2] * zb[2] + zb[3] * zb[3];
#pragma unroll
        for (int o = 1; o < 16; o <<= 1) { u1 += __shfl_xor(u1, o); u2 += __shfl_xor(u2, o); }
        const float mu2 = u1 * (1.0f / 64.0f);
        const float var2 = u2 * (1.0f / 64.0f) - mu2 * mu2;
        const float rstd2 = rsqrtf(var2 + EPS_);
        {
            float4 outv;
            outv.x = sXq[i][d0 + 0] + sGamma[d0 + 0] * ((zb[0] - mu2) * rstd2) + sBeta[d0 + 0];
            outv.y = sXq[i][d0 + 1] + sGamma[d0 + 1] * ((zb[1] - mu2) * rstd2) + sBeta[d0 + 1];
            outv.z = sXq[i][d0 + 2] + sGamma[d0 + 2] * ((zb[2] - mu2) * rstd2) + sBeta[d0 + 2];
            outv.w = sXq[i][d0 + 3] + sGamma[d0 + 3] * ((zb[3] - mu2) * rstd2) + sBeta[d0 + 3];
            *(float4*)(xv_g + n * (MBS_ * HDIM) + t * 4) = outv;
        }
        __syncthreads();

        {
            const float T15 = sTok[15];
            const int d = t >> 2, e0 = (t & 3) * 16;
            float acc[16];
#pragma unroll
            for (int e = 0; e < 16; e++) acc[e] = 0.0f;
#pragma unroll
            for (int j = 0; j < 16; j++) {
                const float lj = sEta[j] * sXk[j][d];
                const float* gr = &sGrad[j][e0];
#pragma unroll
                for (int e = 0; e < 16; e++) acc[e] += lj * gr[e];
            }
            float* wr = &sW1[d][e0];
#pragma unroll
            for (int e = 0; e < 16; e++) wr[e] -= T15 * acc[e];
            if (t < 64) {
                float s = 0.0f;
#pragma unroll
                for (int j = 0; j < 16; j++) s += sEta[j] * sGrad[j][t];
                sB1[t] -= T15 * s;
            }
        }
        __syncthreads();
    }
}

// ======================================================================
// post-norm: gather (B,NH,L,HD) -> LN over C=2048 -> fp32 (B,L,C)
// ======================================================================
__global__ __launch_bounds__(256)
void postln_kernel(const float* __restrict__ Ob, const float* __restrict__ pnw,
                   const float* __restrict__ pnb, float* __restrict__ XN)
{
    const int m = blockIdx.x;
    const int b = m >> 11, l = m & 2047;
    const int t = threadIdx.x;
    float v[8];
    float s1 = 0.0f, s2 = 0.0f;
    const float* bas = Ob + (size_t)b * NHEADS * L_SEQ * HDIM + (size_t)l * HDIM;
#pragma unroll
    for (int j = 0; j < 8; j++) {
        const int c = t + j * 256;
        const int hh = c >> 6, d = c & 63;
        const float x = bas[(size_t)hh * (L_SEQ * HDIM) + d];
        v[j] = x; s1 += x; s2 += x * x;
    }
#pragma unroll
    for (int o = 1; o < 64; o <<= 1) { s1 += __shfl_xor(s1, o); s2 += __shfl_xor(s2, o); }
    __shared__ float r1[4], r2[4];
    const int w = t >> 6;
    if ((t & 63) == 0) { r1[w] = s1; r2[w] = s2; }
    __syncthreads();
    s1 = r1[0] + r1[1] + r1[2] + r1[3];
    s2 = r2[0] + r2[1] + r2[2] + r2[3];
    const float mu = s1 * (1.0f / 2048.0f);
    const float var = s2 * (1.0f / 2048.0f) - mu * mu;
    const float rstd = rsqrtf(var + EPS_);
    float* o = XN + (size_t)m * C_DIM;
#pragma unroll
    for (int j = 0; j < 8; j++) {
        const int c = t + j * 256;
        o[c] = (v[j] - mu) * rstd * pnw[c] + pnb[c];
    }
}

// ======================================================================
extern "C" void kernel_launch(void* const* d_in, const int* in_sizes, int n_in,
                              void* d_out, int out_size, void* d_ws, size_t ws_size,
                              hipStream_t stream)
{
    (void)in_sizes; (void)n_in; (void)out_size;
    const float* hidden  = (const float*)d_in[0];
    const int*   pos_ids = (const int*)d_in[1];
    const float* Wq      = (const float*)d_in[2];
    const float* Wk      = (const float*)d_in[3];
    const float* Wv      = (const float*)d_in[4];
    const float* Wo      = (const float*)d_in[5];
    const float* W1      = (const float*)d_in[6];
    const float* b1      = (const float*)d_in[7];
    const float* wlr     = (const float*)d_in[8];
    const float* lr_bias = (const float*)d_in[9];
    const float* lt      = (const float*)d_in[10];
    const float* lnw     = (const float*)d_in[11];
    const float* lnb     = (const float*)d_in[12];
    const float* pnw     = (const float*)d_in[13];
    const float* pnb     = (const float*)d_in[14];

    const size_t TEN = (size_t)B_DIM * NHEADS * L_SEQ * HDIM;  // 16777216
    float* XQ  = (float*)d_ws;
    float* XK  = XQ + TEN;
    float* XVo = XK + TEN;
    float* LRS = XVo + TEN;                  // B*NH*L = 262144 floats
    const dim3 blk(256);

    // Fast path needs exactly R1's proven footprint: 3*TEN*4 + 1 MB = 202.3 MB
    const size_t FAST_WS = 3 * TEN * 4 + (size_t)262144 * 4;
    if (ws_size >= FAST_WS) {
        // Weight-split scratch lives in d_out (25.2 MB) until final GEMM.
        _Float16* BThi = (_Float16*)d_out;
        _Float16* BTlo = BThi + (size_t)C_DIM * C_DIM;      // +8 MB (16 MB total)

        lr_kernel<<<dim3(B_DIM * L_SEQ), blk, 0, stream>>>(hidden, wlr, lr_bias, LRS);

        const float* Wmats[3] = {Wq, Wk, Wv};
        float* outs[3] = {XQ, XK, XVo};
        for (int p = 0; p < 3; p++) {
            wtrans_kernel<<<dim3(64, 64), blk, 0, stream>>>(Wmats[p], BThi, BTlo, C_DIM);
            gemm_af32<<<dim3(16, 64), blk, 0, stream>>>(hidden, BThi, BTlo,
                                                        outs[p], 0, (p < 2) ? 1 : 0);
        }
        scan_kernel<<<dim3(B_DIM * NHEADS), blk, 0, stream>>>(XQ, XK, XVo, LRS,
                                                              W1, b1, lt, lnw, lnb);
        // After scan: XQ region free -> XN (fp32); XK region free -> Wo splits.
        float* XN = XQ;
        _Float16* WThi = (_Float16*)XK;
        _Float16* WTlo = WThi + (size_t)OUT_DIM * C_DIM;    // 6.3 MB total
        postln_kernel<<<dim3(B_DIM * L_SEQ), blk, 0, stream>>>(XVo, pnw, pnb, XN);
        wtrans_kernel<<<dim3(24, 64), blk, 0, stream>>>(Wo, WThi, WTlo, OUT_DIM);
        gemm_af32<<<dim3(6, 64), blk, 0, stream>>>(XN, WThi, WTlo,
                                                   (float*)d_out, 1, 0);
    } else {
        // Fallback: proven R1 fp32 path
        float* XN = XQ;
        sgemm_kernel<<<dim3(16, 64), blk, 0, stream>>>(hidden, Wq, XQ,  C_DIM, C_DIM, 0);
        sgemm_kernel<<<dim3(16, 64), blk, 0, stream>>>(hidden, Wk, XK,  C_DIM, C_DIM, 0);
        sgemm_kernel<<<dim3(16, 64), blk, 0, stream>>>(hidden, Wv, XVo, C_DIM, C_DIM, 0);
        lr_kernel<<<dim3(B_DIM * L_SEQ), blk, 0, stream>>>(hidden, wlr, lr_bias, LRS);
        rope_kernel<<<dim3(32768), blk, 0, stream>>>(XQ, pos_ids);
        rope_kernel<<<dim3(32768), blk, 0, stream>>>(XK, pos_ids);
        scan_kernel<<<dim3(B_DIM * NHEADS), blk, 0, stream>>>(XQ, XK, XVo, LRS,
                                                              W1, b1, lt, lnw, lnb);
        postln_kernel<<<dim3(B_DIM * L_SEQ), blk, 0, stream>>>(XVo, pnw, pnb, XN);
        sgemm_kernel<<<dim3(6, 64), blk, 0, stream>>>(XN, Wo, (float*)d_out, OUT_DIM, C_DIM, 1);
    }
    (void)pos_ids;
}

// Round 4
// 1474.378 us; speedup vs baseline: 2.6085x; 1.1501x over previous
//
#include <hip/hip_runtime.h>
#include <cstddef>
#include <cstdint>

// Problem constants
#define B_DIM   4
#define L_SEQ   2048
#define C_DIM   2048
#define OUT_DIM 768
#define NHEADS  32
#define HDIM    64
#define MBS_    16
#define NMINI   128
#define EPS_    1e-6f

typedef _Float16 half8 __attribute__((ext_vector_type(8)));
typedef float floatx4 __attribute__((ext_vector_type(4)));

__device__ __forceinline__ void glds16(const void* g, void* l) {
    __builtin_amdgcn_global_load_lds(
        (const __attribute__((address_space(1))) uint32_t*)g,
        (__attribute__((address_space(3))) uint32_t*)l, 16, 0, 0);
}

__device__ __forceinline__ void split8(const float4 a, const float4 b,
                                       half8& hi, half8& lo) {
    const float x[8] = {a.x, a.y, a.z, a.w, b.x, b.y, b.z, b.w};
#pragma unroll
    for (int e = 0; e < 8; e++) {
        const _Float16 h = (_Float16)x[e];
        hi[e] = h;
        lo[e] = (_Float16)(x[e] - (float)h);
    }
}

// ======================================================================
// MFMA GEMM, A = fp32 [M][2048] split on the fly; B = fp16 hi/lo [N][K].
// (unchanged from R3 — passed, MFMA path)
// ======================================================================
__global__ __launch_bounds__(256)
void gemm_af32(const float* __restrict__ A,
               const _Float16* __restrict__ Bhi, const _Float16* __restrict__ Blo,
               float* __restrict__ Cout, int mode, int doRope)
{
    __shared__ __align__(16) float    sA[4096];
    __shared__ __align__(16) _Float16 sBhi[4096];
    __shared__ __align__(16) _Float16 sBlo[4096];
    const int tid = threadIdx.x;
    const int m0 = blockIdx.y * 128, n0 = blockIdx.x * 128;
    const int K = 2048;

    size_t gA[4]; float* lA[4];
#pragma unroll
    for (int I = 0; I < 4; I++) {
        const int c = I * 256 + tid;
        const int row = c >> 3, seg = (c & 7) ^ (row & 7);
        gA[I] = (size_t)(m0 + row) * K + seg * 4;
        lA[I] = &sA[c * 4];
    }
    size_t gB[2]; _Float16 *lBh[2], *lBl[2];
#pragma unroll
    for (int I = 0; I < 2; I++) {
        const int c = I * 256 + tid;
        const int row = c >> 2, seg = (c & 3) ^ ((row >> 1) & 3);
        gB[I] = (size_t)(n0 + row) * K + seg * 8;
        lBh[I] = &sBhi[c * 8];
        lBl[I] = &sBlo[c * 8];
    }

    const int lane = tid & 63, quad = lane >> 4, lc = lane & 15;
    const int wv = tid >> 6, wm = wv & 1, wn = wv >> 1;
    int offA0[4], offA1[4], offB[4];
#pragma unroll
    for (int i = 0; i < 4; i++) {
        const int rA = wm * 64 + i * 16 + lc;
        offA0[i] = (rA * 8 + ((2 * quad)     ^ (rA & 7))) * 4;
        offA1[i] = (rA * 8 + ((2 * quad + 1) ^ (rA & 7))) * 4;
    }
#pragma unroll
    for (int j = 0; j < 4; j++) {
        const int rB = wn * 64 + j * 16 + lc;
        offB[j] = (rB * 4 + (quad ^ ((rB >> 1) & 3))) * 8;
    }

    floatx4 acc[4][4];
#pragma unroll
    for (int i = 0; i < 4; i++)
#pragma unroll
        for (int j = 0; j < 4; j++) acc[i][j] = (floatx4)0.0f;

    for (int k0 = 0; k0 < K; k0 += 32) {
        __syncthreads();
#pragma unroll
        for (int I = 0; I < 4; I++) glds16(A + gA[I] + k0, lA[I]);
#pragma unroll
        for (int I = 0; I < 2; I++) {
            glds16(Bhi + gB[I] + k0, lBh[I]);
            glds16(Blo + gB[I] + k0, lBl[I]);
        }
        __syncthreads();

        half8 ah[4], al[4], bh[4], bl[4];
#pragma unroll
        for (int i = 0; i < 4; i++) {
            const float4 va = *(const float4*)&sA[offA0[i]];
            const float4 vb = *(const float4*)&sA[offA1[i]];
            split8(va, vb, ah[i], al[i]);
        }
#pragma unroll
        for (int j = 0; j < 4; j++) {
            bh[j] = *(const half8*)&sBhi[offB[j]];
            bl[j] = *(const half8*)&sBlo[offB[j]];
        }
#pragma unroll
        for (int i = 0; i < 4; i++)
#pragma unroll
            for (int j = 0; j < 4; j++) {
                acc[i][j] = __builtin_amdgcn_mfma_f32_16x16x32_f16(ah[i], bh[j], acc[i][j], 0, 0, 0);
                acc[i][j] = __builtin_amdgcn_mfma_f32_16x16x32_f16(ah[i], bl[j], acc[i][j], 0, 0, 0);
                acc[i][j] = __builtin_amdgcn_mfma_f32_16x16x32_f16(al[i], bh[j], acc[i][j], 0, 0, 0);
            }
    }

    float cs[4][4], sn[4][4];
    if (doRope) {
#pragma unroll
        for (int j = 0; j < 4; j++) {
            const int ii = ((j * 16 + lc) & 63) >> 1;
            const float invf = expf(-(float)ii * 0.28782313662425574f);
#pragma unroll
            for (int r = 0; r < 4; r++) {
                const float ang = (float)(quad * 4 + r) * invf;
                sincosf(ang, &sn[j][r], &cs[j][r]);
            }
        }
    }
    const int oddcol = lc & 1;
#pragma unroll
    for (int i = 0; i < 4; i++) {
#pragma unroll
        for (int j = 0; j < 4; j++) {
            floatx4 v = acc[i][j];
            if (doRope) {
#pragma unroll
                for (int r = 0; r < 4; r++) {
                    const float partner = __shfl_xor(v[r], 1);
                    v[r] = v[r] * cs[j][r] + partner * (oddcol ? sn[j][r] : -sn[j][r]);
                }
            }
            const int n = n0 + wn * 64 + j * 16 + lc;
            if (mode == 0) {
                const int h = (n >> 6) & 31, d = n & 63;
#pragma unroll
                for (int r = 0; r < 4; r++) {
                    const int m = m0 + wm * 64 + i * 16 + quad * 4 + r;
                    const int b = m >> 11, li = m & 2047;
                    Cout[((size_t)(b * 32 + h) * 2048 + li) * 64 + d] = v[r];
                }
            } else {
#pragma unroll
                for (int r = 0; r < 4; r++) {
                    const int m = m0 + wm * 64 + i * 16 + quad * 4 + r;
                    Cout[(size_t)m * OUT_DIM + n] = v[r];
                }
            }
        }
    }
}

// ======================================================================
// Weight transpose + split
// ======================================================================
__global__ __launch_bounds__(256)
void wtrans_kernel(const float* __restrict__ W, _Float16* __restrict__ BThi,
                   _Float16* __restrict__ BTlo, int Nw)
{
    __shared__ float tile[32][33];
    const int t = threadIdx.x, tx = t & 31, ty = t >> 5;
    const int n0 = blockIdx.x * 32, k0 = blockIdx.y * 32;
    const int K = 2048;
#pragma unroll
    for (int r = 0; r < 4; r++)
        tile[ty + r * 8][tx] = W[(size_t)(k0 + ty + r * 8) * Nw + n0 + tx];
    __syncthreads();
#pragma unroll
    for (int r = 0; r < 4; r++) {
        const float val = tile[tx][ty + r * 8];
        const _Float16 hh = (_Float16)val;
        const size_t o = (size_t)(n0 + ty + r * 8) * K + k0 + tx;
        BThi[o] = hh;
        BTlo[o] = (_Float16)(val - (float)hh);
    }
}

// ======================================================================
// ttt_lr sigmoid
// ======================================================================
__global__ __launch_bounds__(256)
void lr_kernel(const float* __restrict__ hidden, const float* __restrict__ wlr,
               const float* __restrict__ lr_bias, float* __restrict__ lrs)
{
    __shared__ float sRow[2048];
    __shared__ float sPart[32][9];
    const int m = blockIdx.x;
    const int t = threadIdx.x;
    const float* row = hidden + (size_t)m * C_DIM;
#pragma unroll
    for (int j = 0; j < 8; j++) sRow[t + j * 256] = row[t + j * 256];
    __syncthreads();
    const int h = t >> 3, p = t & 7;
    const float* w = wlr + (size_t)h * C_DIM;
    float s = 0.0f;
#pragma unroll 8
    for (int k = 0; k < 64; k++) {
        const int c = k * 32 + p * 4;
        const float4 a = *(const float4*)(sRow + c);
        const float4 b = *(const float4*)(w + c);
        s += a.x * b.x + a.y * b.y + a.z * b.z + a.w * b.w;
    }
    sPart[h][p] = s;
    __syncthreads();
    if (t < 32) {
        float v = 0.0f;
#pragma unroll
        for (int p2 = 0; p2 < 8; p2++) v += sPart[t][p2];
        v += lr_bias[t];
        const float sig = 1.0f / (1.0f + expf(-v));
        lrs[((size_t)(m >> 11) * NHEADS + t) * L_SEQ + (m & 2047)] = sig;
    }
}

// ======================================================================
// MFMA TTT scan: one block (4 waves) per (b,h). Wave w owns output
// columns [16w,16w+16). W1 state kept transposed (W1T[n][k]) in
// registers (C-layout) + LDS (cell-XOR) for B-fragment reads.
// All matmuls are split-fp16 3-pass (fp32-accurate).
// ======================================================================
__global__ __launch_bounds__(256, 1)
void scan_mfma(const float* __restrict__ XQ, const float* __restrict__ XK,
               float* __restrict__ XVo, const float* __restrict__ LRS,
               const float* __restrict__ W1i, const float* __restrict__ b1i,
               const float* __restrict__ lt, const float* __restrict__ lnw,
               const float* __restrict__ lnb)
{
    // cell-XOR layout: addr(row,c) = row*64 + (((c>>2)^(row&15))<<2) + (c&3)
    __shared__ __align__(16) float sXq[1024];     // [16][64]
    __shared__ __align__(16) float sXk[1024];     // [16][64]
    __shared__ __align__(16) float sXv[16 * 68];  // plain, stride 68
    __shared__ __align__(16) float sW1T[4096];    // [64 n][64 k] cell-XOR
    __shared__ __align__(16) float sGt[64 * 36];  // gradT[n][j], j 16..31 zero
    __shared__ __align__(16) float sKt[64 * 36];  // lasteta*Xk^T [k][j]
    __shared__ __align__(16) float sCf[16 * 36];  // -coeff[i][j]
    __shared__ __align__(16) float sRed[16 * 8];  // [row][s1:w | s2:4+w]
    __shared__ float sMu[16], sRstd[16], sG1[16], sG2[16];
    __shared__ float sB1[64], sGam[64], sBet[64];
    __shared__ __align__(16) float sEta[32];      // [16..31] stay zero
    __shared__ float sTok[16];

    const int bh = blockIdx.x, h = bh & 31;
    const int t = threadIdx.x;
    const int lane = t & 63, q = lane >> 4, lc = lane & 15;
    const int w = t >> 6;
    const int col = w * 16 + lc;     // this lane's output column n
    const int iRow = t >> 4;         // phase-1 row (0..15)
    const int c0 = (t & 15) * 4;     // phase-1 col base
    const int cellP = (t & 15) ^ (iRow & 15);   // phase-1 XOR cell

    if (t < 64) { sB1[t] = b1i[h * 64 + t]; sGam[t] = lnw[h * 64 + t]; sBet[t] = lnb[h * 64 + t]; }
    if (t < 16) sTok[t] = fmaxf(1.0f / (float)(t + 1) + lt[t], 0.0f);
    if (t < 32) sEta[t] = 0.0f;
    // zero j=16..31 pads
    for (int idx = t; idx < 1024; idx += 256) {
        const int r = idx >> 4, c = 16 + (idx & 15);
        sGt[r * 36 + c] = 0.0f;
        sKt[r * 36 + c] = 0.0f;
    }
    { const int r = t >> 4, c = 16 + (t & 15); sCf[r * 36 + c] = 0.0f; }

    // W1 state regs (C-layout): w1s[t4][r] = W1T[16w+4q+r][16t4+lc] = W1[h][k][n]
    float w1s[4][4];
#pragma unroll
    for (int t4 = 0; t4 < 4; t4++)
#pragma unroll
        for (int r = 0; r < 4; r++)
            w1s[t4][r] = W1i[h * 4096 + (16 * t4 + lc) * 64 + (16 * w + 4 * q + r)];
    // initial W1T -> LDS (cell-XOR)
#pragma unroll
    for (int t4 = 0; t4 < 4; t4++)
#pragma unroll
        for (int r = 0; r < 4; r++) {
            const int nn = 16 * w + 4 * q + r, k = 16 * t4 + lc;
            sW1T[nn * 64 + ((((k >> 2) ^ (nn & 15)) << 2) | (k & 3))] = w1s[t4][r];
        }
    __syncthreads();

    const float tok15 = sTok[15];
    const float gamC = sGam[col], betC = sBet[col];
    float tokR[4];
#pragma unroll
    for (int r = 0; r < 4; r++) tokR[r] = sTok[4 * q + r];

    const size_t base = (size_t)bh * L_SEQ * HDIM;
    const float* xq_g = XQ + base;
    const float* xk_g = XK + base;
    float* xv_g = XVo + base;
    const float* lr_g = LRS + (size_t)bh * L_SEQ;

    // preload minibatch 0
    float4 cq = *(const float4*)(xq_g + t * 4);
    float4 ck = *(const float4*)(xk_g + t * 4);
    float4 cv = *(const float4*)(xv_g + t * 4);
    float clr = lr_g[t & 15];

    for (int n = 0; n < NMINI; n++) {
        // ---- phase 1: stage current minibatch ----
        *(float4*)&sXq[iRow * 64 + (cellP << 2)] = cq;
        *(float4*)&sXk[iRow * 64 + (cellP << 2)] = ck;
        *(float4*)&sXv[iRow * 68 + c0] = cv;
        if (t < 16) sEta[t] = clr * (1.0f / 64.0f);
        const int np = (n + 1) & (NMINI - 1);
        const float4 nq = *(const float4*)(xq_g + np * 1024 + t * 4);
        const float4 nk = *(const float4*)(xk_g + np * 1024 + t * 4);
        const float4 nv = *(const float4*)(xv_g + np * 1024 + t * 4);
        const float nlr = lr_g[np * 16 + (t & 15)];
        __syncthreads();   // A

        // lasteta-folded Xk^T
        {
            const float le = tok15 * sEta[iRow];
            sKt[(c0 + 0) * 36 + iRow] = ck.x * le;
            sKt[(c0 + 1) * 36 + iRow] = ck.y * le;
            sKt[(c0 + 2) * 36 + iRow] = ck.z * le;
            sKt[(c0 + 3) * 36 + iRow] = ck.w * le;
        }

        // ---- fragments ----
        half8 qh[2], ql[2], kh[2], kl[2], wh[2], wl[2];
#pragma unroll
        for (int f = 0; f < 2; f++) {
            const int ca = (8 * f + 2 * q) ^ lc, cb = (8 * f + 2 * q + 1) ^ lc;
            {
                const float4 u0 = *(const float4*)&sXq[lc * 64 + ca * 4];
                const float4 u1 = *(const float4*)&sXq[lc * 64 + cb * 4];
                split8(u0, u1, qh[f], ql[f]);
            }
            {
                const float4 u0 = *(const float4*)&sXk[lc * 64 + ca * 4];
                const float4 u1 = *(const float4*)&sXk[lc * 64 + cb * 4];
                split8(u0, u1, kh[f], kl[f]);
            }
            {
                const int rw = 16 * w + lc;
                const float4 u0 = *(const float4*)&sW1T[rw * 64 + ca * 4];
                const float4 u1 = *(const float4*)&sW1T[rw * 64 + cb * 4];
                split8(u0, u1, wh[f], wl[f]);
            }
        }

        // ---- forward MFMAs ----
        floatx4 z1a = (floatx4)0.0f, zba = (floatx4)0.0f, at = (floatx4)0.0f;
#pragma unroll
        for (int f = 0; f < 2; f++) {
            z1a = __builtin_amdgcn_mfma_f32_16x16x32_f16(kh[f], wh[f], z1a, 0, 0, 0);
            z1a = __builtin_amdgcn_mfma_f32_16x16x32_f16(kh[f], wl[f], z1a, 0, 0, 0);
            z1a = __builtin_amdgcn_mfma_f32_16x16x32_f16(kl[f], wh[f], z1a, 0, 0, 0);
            zba = __builtin_amdgcn_mfma_f32_16x16x32_f16(qh[f], wh[f], zba, 0, 0, 0);
            zba = __builtin_amdgcn_mfma_f32_16x16x32_f16(qh[f], wl[f], zba, 0, 0, 0);
            zba = __builtin_amdgcn_mfma_f32_16x16x32_f16(ql[f], wh[f], zba, 0, 0, 0);
        }
        if (w == 0) {
#pragma unroll
            for (int f = 0; f < 2; f++) {
                at = __builtin_amdgcn_mfma_f32_16x16x32_f16(qh[f], kh[f], at, 0, 0, 0);
                at = __builtin_amdgcn_mfma_f32_16x16x32_f16(qh[f], kl[f], at, 0, 0, 0);
                at = __builtin_amdgcn_mfma_f32_16x16x32_f16(ql[f], kh[f], at, 0, 0, 0);
            }
        }

        // ---- Z1 stats ----
        const float b1c = sB1[col];
        float z[4], s1[4], s2[4];
#pragma unroll
        for (int r = 0; r < 4; r++) { z[r] = z1a[r] + b1c; s1[r] = z[r]; s2[r] = z[r] * z[r]; }
#pragma unroll
        for (int o = 1; o < 16; o <<= 1)
#pragma unroll
            for (int r = 0; r < 4; r++) { s1[r] += __shfl_xor(s1[r], o); s2[r] += __shfl_xor(s2[r], o); }
        if (lc == 0)
#pragma unroll
            for (int r = 0; r < 4; r++) {
                const int row = 4 * q + r;
                sRed[row * 8 + w] = s1[r];
                sRed[row * 8 + 4 + w] = s2[r];
            }
        __syncthreads();   // B
        if (t < 16) {
            const float4 a = *(const float4*)&sRed[t * 8];
            const float4 b = *(const float4*)&sRed[t * 8 + 4];
            const float mu = (a.x + a.y + a.z + a.w) * (1.0f / 64.0f);
            const float ex2 = (b.x + b.y + b.z + b.w) * (1.0f / 64.0f);
            sMu[t] = mu;
            sRstd[t] = rsqrtf(ex2 - mu * mu + EPS_);
        }
        __syncthreads();   // C

        // ---- grad (LN-L2 bwd) ----
        float gg[4], xh[4];
#pragma unroll
        for (int r = 0; r < 4; r++) {
            const int row = 4 * q + r;
            const float mu = sMu[row], rs = sRstd[row];
            xh[r] = (z[r] - mu) * rs;
            const float xkv = sXk[row * 64 + (((((col >> 2) ^ row) & 15) << 2) | (col & 3))];
            const float tgt = sXv[row * 68 + col] - xkv;
            gg[r] = (gamC * xh[r] + betC - tgt) * gamC;
            s1[r] = gg[r]; s2[r] = gg[r] * xh[r];
        }
#pragma unroll
        for (int o = 1; o < 16; o <<= 1)
#pragma unroll
            for (int r = 0; r < 4; r++) { s1[r] += __shfl_xor(s1[r], o); s2[r] += __shfl_xor(s2[r], o); }
        if (lc == 0)
#pragma unroll
            for (int r = 0; r < 4; r++) {
                const int row = 4 * q + r;
                sRed[row * 8 + w] = s1[r];
                sRed[row * 8 + 4 + w] = s2[r];
            }
        __syncthreads();   // D1
        if (t < 16) {
            const float4 a = *(const float4*)&sRed[t * 8];
            const float4 b = *(const float4*)&sRed[t * 8 + 4];
            sG1[t] = a.x + a.y + a.z + a.w;
            sG2[t] = b.x + b.y + b.z + b.w;
        }
        __syncthreads();   // D2
#pragma unroll
        for (int r = 0; r < 4; r++) {
            const int row = 4 * q + r;
            const float rs = sRstd[row];
            const float gr = (64.0f * gg[r] - sG1[row] - xh[r] * sG2[row]) * rs * (1.0f / 64.0f);
            sGt[col * 36 + row] = gr;
        }
        // ---- coeff (wave 0) ----
        if (w == 0) {
            const float ej = sEta[lc];
#pragma unroll
            for (int r = 0; r < 4; r++) {
                const int i = 4 * q + r;
                const float cf = (lc <= i) ? -tokR[r] * ej * (at[r] + 1.0f) : 0.0f;
                sCf[i * 36 + lc] = cf;
            }
        }
        __syncthreads();   // E

        // ---- Zbar -= coeff@grad;  W1 update ----
        half8 cfh, cfl, gth, gtl;
        {
            const float4 u0 = *(const float4*)&sCf[lc * 36 + 8 * q];
            const float4 u1 = *(const float4*)&sCf[lc * 36 + 8 * q + 4];
            split8(u0, u1, cfh, cfl);
        }
        {
            const int rw = 16 * w + lc;
            const float4 u0 = *(const float4*)&sGt[rw * 36 + 8 * q];
            const float4 u1 = *(const float4*)&sGt[rw * 36 + 8 * q + 4];
            split8(u0, u1, gth, gtl);
        }
        zba = __builtin_amdgcn_mfma_f32_16x16x32_f16(cfh, gth, zba, 0, 0, 0);
        zba = __builtin_amdgcn_mfma_f32_16x16x32_f16(cfh, gtl, zba, 0, 0, 0);
        zba = __builtin_amdgcn_mfma_f32_16x16x32_f16(cfl, gth, zba, 0, 0, 0);
#pragma unroll
        for (int t4 = 0; t4 < 4; t4++) {
            half8 kth, ktl;
            const float4 u0 = *(const float4*)&sKt[(16 * t4 + lc) * 36 + 8 * q];
            const float4 u1 = *(const float4*)&sKt[(16 * t4 + lc) * 36 + 8 * q + 4];
            split8(u0, u1, kth, ktl);
            floatx4 up = (floatx4)0.0f;
            up = __builtin_amdgcn_mfma_f32_16x16x32_f16(gth, kth, up, 0, 0, 0);
            up = __builtin_amdgcn_mfma_f32_16x16x32_f16(gth, ktl, up, 0, 0, 0);
            up = __builtin_amdgcn_mfma_f32_16x16x32_f16(gtl, kth, up, 0, 0, 0);
#pragma unroll
            for (int r = 0; r < 4; r++) w1s[t4][r] -= up[r];
        }

        // ---- Zbar stats ----
        float z2[4];
#pragma unroll
        for (int r = 0; r < 4; r++) { z2[r] = zba[r] + b1c; s1[r] = z2[r]; s2[r] = z2[r] * z2[r]; }
#pragma unroll
        for (int o = 1; o < 16; o <<= 1)
#pragma unroll
            for (int r = 0; r < 4; r++) { s1[r] += __shfl_xor(s1[r], o); s2[r] += __shfl_xor(s2[r], o); }
        if (lc == 0)
#pragma unroll
            for (int r = 0; r < 4; r++) {
                const int row = 4 * q + r;
                sRed[row * 8 + w] = s1[r];
                sRed[row * 8 + 4 + w] = s2[r];
            }
        __syncthreads();   // F1
        if (t < 16) {
            const float4 a = *(const float4*)&sRed[t * 8];
            const float4 b = *(const float4*)&sRed[t * 8 + 4];
            const float mu = (a.x + a.y + a.z + a.w) * (1.0f / 64.0f);
            const float ex2 = (b.x + b.y + b.z + b.w) * (1.0f / 64.0f);
            sMu[t] = mu;
            sRstd[t] = rsqrtf(ex2 - mu * mu + EPS_);
        }
        __syncthreads();   // F2

        // ---- out = xq + LN(Zbar) ----
#pragma unroll
        for (int r = 0; r < 4; r++) {
            const int row = 4 * q + r;
            const float mu = sMu[row], rs = sRstd[row];
            const float xqv = sXq[row * 64 + (((((col >> 2) ^ row) & 15) << 2) | (col & 3))];
            xv_g[n * 1024 + row * 64 + col] = xqv + gamC * ((z2[r] - mu) * rs) + betC;
        }

        // ---- b1 update ----
        {
            const float4 e0 = *(const float4*)&sEta[8 * q];
            const float4 e1 = *(const float4*)&sEta[8 * q + 4];
            const float ev[8] = {e0.x, e0.y, e0.z, e0.w, e1.x, e1.y, e1.z, e1.w};
            float p = 0.0f;
#pragma unroll
            for (int jj = 0; jj < 8; jj++)
                p += ((float)gth[jj] + (float)gtl[jj]) * ev[jj];
            p += __shfl_xor(p, 16);
            if (q == 0) sB1[col] -= tok15 * p;
        }

        // ---- W1T regs -> LDS for next step ----
#pragma unroll
        for (int t4 = 0; t4 < 4; t4++)
#pragma unroll
            for (int r = 0; r < 4; r++) {
                const int nn = 16 * w + 4 * q + r, k = 16 * t4 + lc;
                sW1T[nn * 64 + ((((k >> 2) ^ (nn & 15)) << 2) | (k & 3))] = w1s[t4][r];
            }
        __syncthreads();   // G
        cq = nq; ck = nk; cv = nv; clr = nlr;
    }
}

// ======================================================================
// post-norm: gather (B,NH,L,HD) -> LN over C=2048 -> fp32 (B,L,C)
// ======================================================================
__global__ __launch_bounds__(256)
void postln_kernel(const float* __restrict__ Ob, const float* __restrict__ pnw,
                   const float* __restrict__ pnb, float* __restrict__ XN)
{
    const int m = blockIdx.x;
    const int b = m >> 11, l = m & 2047;
    const int t = threadIdx.x;
    float v[8];
    float s1 = 0.0f, s2 = 0.0f;
    const float* bas = Ob + (size_t)b * NHEADS * L_SEQ * HDIM + (size_t)l * HDIM;
#pragma unroll
    for (int j = 0; j < 8; j++) {
        const int c = t + j * 256;
        const int hh = c >> 6, d = c & 63;
        const float x = bas[(size_t)hh * (L_SEQ * HDIM) + d];
        v[j] = x; s1 += x; s2 += x * x;
    }
#pragma unroll
    for (int o = 1; o < 64; o <<= 1) { s1 += __shfl_xor(s1, o); s2 += __shfl_xor(s2, o); }
    __shared__ float r1[4], r2[4];
    const int w = t >> 6;
    if ((t & 63) == 0) { r1[w] = s1; r2[w] = s2; }
    __syncthreads();
    s1 = r1[0] + r1[1] + r1[2] + r1[3];
    s2 = r2[0] + r2[1] + r2[2] + r2[3];
    const float mu = s1 * (1.0f / 2048.0f);
    const float var = s2 * (1.0f / 2048.0f) - mu * mu;
    const float rstd = rsqrtf(var + EPS_);
    float* o = XN + (size_t)m * C_DIM;
#pragma unroll
    for (int j = 0; j < 8; j++) {
        const int c = t + j * 256;
        o[c] = (v[j] - mu) * rstd * pnw[c] + pnb[c];
    }
}

// ======================================================================
extern "C" void kernel_launch(void* const* d_in, const int* in_sizes, int n_in,
                              void* d_out, int out_size, void* d_ws, size_t ws_size,
                              hipStream_t stream)
{
    (void)in_sizes; (void)n_in; (void)out_size;
    const float* hidden  = (const float*)d_in[0];
    const float* Wq      = (const float*)d_in[2];
    const float* Wk      = (const float*)d_in[3];
    const float* Wv      = (const float*)d_in[4];
    const float* Wo      = (const float*)d_in[5];
    const float* W1      = (const float*)d_in[6];
    const float* b1      = (const float*)d_in[7];
    const float* wlr     = (const float*)d_in[8];
    const float* lr_bias = (const float*)d_in[9];
    const float* lt      = (const float*)d_in[10];
    const float* lnw     = (const float*)d_in[11];
    const float* lnb     = (const float*)d_in[12];
    const float* pnw     = (const float*)d_in[13];
    const float* pnb     = (const float*)d_in[14];

    const size_t TEN = (size_t)B_DIM * NHEADS * L_SEQ * HDIM;  // 16777216
    float* XQ  = (float*)d_ws;
    float* XK  = XQ + TEN;
    float* XVo = XK + TEN;
    float* LRS = XVo + TEN;
    const dim3 blk(256);

    // Weight-split scratch lives in d_out (25.2 MB) until the final GEMM.
    _Float16* BThi = (_Float16*)d_out;
    _Float16* BTlo = BThi + (size_t)C_DIM * C_DIM;

    lr_kernel<<<dim3(B_DIM * L_SEQ), blk, 0, stream>>>(hidden, wlr, lr_bias, LRS);

    const float* Wmats[3] = {Wq, Wk, Wv};
    float* outs[3] = {XQ, XK, XVo};
    for (int p = 0; p < 3; p++) {
        wtrans_kernel<<<dim3(64, 64), blk, 0, stream>>>(Wmats[p], BThi, BTlo, C_DIM);
        gemm_af32<<<dim3(16, 64), blk, 0, stream>>>(hidden, BThi, BTlo,
                                                    outs[p], 0, (p < 2) ? 1 : 0);
    }
    scan_mfma<<<dim3(B_DIM * NHEADS), blk, 0, stream>>>(XQ, XK, XVo, LRS,
                                                        W1, b1, lt, lnw, lnb);
    float* XN = XQ;
    _Float16* WThi = (_Float16*)XK;
    _Float16* WTlo = WThi + (size_t)OUT_DIM * C_DIM;
    postln_kernel<<<dim3(B_DIM * L_SEQ), blk, 0, stream>>>(XVo, pnw, pnb, XN);
    wtrans_kernel<<<dim3(24, 64), blk, 0, stream>>>(Wo, WThi, WTlo, OUT_DIM);
    gemm_af32<<<dim3(6, 64), blk, 0, stream>>>(XN, WThi, WTlo,
                                               (float*)d_out, 1, 0);
}